// Round 1
// baseline (21528.796 us; speedup 1.0000x reference)
//
#include <hip/hip_runtime.h>
#include <hip/hip_bf16.h>
#include <hip/hip_cooperative_groups.h>

namespace cg = cooperative_groups;

using bf16 = __hip_bfloat16;
typedef short bf16x8_t __attribute__((ext_vector_type(8)));   // 8 bf16 (4 VGPRs)
typedef float f32x4_t __attribute__((ext_vector_type(4)));

// sizes
#define Bsz 32
#define Ssz 128
#define Tsz 128
#define Esz 256
#define Hsz 512
#define VTsz 16000

__device__ inline float sigm(float x)      { return 1.f / (1.f + __expf(-x)); }
__device__ inline float tanh_fast(float x) { return 1.f - 2.f / (1.f + __expf(2.f * x)); }

__device__ inline unsigned pack2(float x, float y) {
  unsigned short lo = __builtin_bit_cast(unsigned short, __float2bfloat16(x));
  unsigned short hi = __builtin_bit_cast(unsigned short, __float2bfloat16(y));
  return (unsigned)lo | ((unsigned)hi << 16);
}

__device__ inline uint4 f32x8_to_bf16x8(const float* s) {
  float4 a = *(const float4*)s;
  float4 b = *(const float4*)(s + 4);
  uint4 r;
  r.x = pack2(a.x, a.y); r.y = pack2(a.z, a.w);
  r.z = pack2(b.x, b.y); r.w = pack2(b.z, b.w);
  return r;
}

// ---------------------------------------------------------------------------
// Embedding gather + f32->bf16.
// ---------------------------------------------------------------------------
__global__ __launch_bounds__(256) void embed_gather(
    const int* __restrict__ src, const int* __restrict__ tgt,
    const float* __restrict__ es, const float* __restrict__ et,
    bf16* __restrict__ xs_b, bf16* __restrict__ ys_b)
{
  int idx = blockIdx.x * 256 + threadIdx.x;     // 0 .. 262143
  int which = idx >> 17;                        // 131072 chunks per tensor
  int c = idx & 131071;
  int row = c >> 5;                             // 32 chunks per row (E=256)
  int cc = c & 31;
  if (which == 0) {
    int tok = src[row];
    *(uint4*)(xs_b + (size_t)row * Esz + cc * 8) =
        f32x8_to_bf16x8(es + (size_t)tok * Esz + cc * 8);
  } else {
    int tok = tgt[row];
    *(uint4*)(ys_b + (size_t)row * Esz + cc * 8) =
        f32x8_to_bf16x8(et + (size_t)tok * Esz + cc * 8);
  }
}

// ---------------------------------------------------------------------------
// Weight transposes (f32 src -> bf16 dst, k-major for recurrent kernels).
// ---------------------------------------------------------------------------
__global__ __launch_bounds__(256) void transpose_w(
    const float* __restrict__ enc_Whh, const float* __restrict__ dec_Whh,
    const float* __restrict__ attn_W,  const float* __restrict__ dec_Wih,
    bf16* __restrict__ encWhh_t, bf16* __restrict__ Wcat_t, bf16* __restrict__ Wihctx_t)
{
  int idx = blockIdx.x * 256 + threadIdx.x;
  const int N1 = 512 * 1536, N2 = 512 * 2048;
  if (idx < N1) {
    int k = idx / 1536, j = idx % 1536;
    encWhh_t[idx] = __float2bfloat16(enc_Whh[(size_t)j * 512 + k]);
  } else if (idx < N1 + N2) {
    int r = idx - N1;
    int k = r / 2048, j = r % 2048;
    float v = (j < 1536) ? dec_Whh[(size_t)j * 512 + k]
                         : attn_W[(size_t)(j - 1536) * 1024 + k];
    Wcat_t[r] = __float2bfloat16(v);
  } else {
    int r = idx - N1 - N2;
    int k = r / 1536, j = r % 1536;
    Wihctx_t[r] = __float2bfloat16(dec_Wih[(size_t)j * 768 + 256 + k]);
  }
}

// ---------------------------------------------------------------------------
// Pack GEMM B-operands f32 -> bf16 (row-major, packed).
// ---------------------------------------------------------------------------
__global__ __launch_bounds__(256) void pack_weights(
    const float* __restrict__ enc_Wih, const float* __restrict__ dec_Wih,
    const float* __restrict__ attn_W,  const float* __restrict__ fc_W,
    bf16* __restrict__ encWih_b, bf16* __restrict__ decWihY_b,
    bf16* __restrict__ attnWe_b, bf16* __restrict__ fcW_b)
{
  int idx = blockIdx.x * 256 + threadIdx.x;
  const int R1 = 1536 * 256, R2 = 1536 * 256, R3 = 512 * 512;
  if (idx < R1) {
    encWih_b[idx] = __float2bfloat16(enc_Wih[idx]);
  } else if (idx < R1 + R2) {
    int r = idx - R1;
    int row = r >> 8, col = r & 255;
    decWihY_b[r] = __float2bfloat16(dec_Wih[(size_t)row * 768 + col]);
  } else if (idx < R1 + R2 + R3) {
    int r = idx - R1 - R2;
    int row = r >> 9, col = r & 511;
    attnWe_b[r] = __float2bfloat16(attn_W[(size_t)row * 1024 + 512 + col]);
  } else {
    int r = idx - R1 - R2 - R3;
    fcW_b[r] = __float2bfloat16(fc_W[r]);
  }
}

// ---------------------------------------------------------------------------
// MFMA GEMM: C[m,n] = sum_k A[m,k]*B[n,k] + bias[n]. 128x128 tile, BK=64.
// ---------------------------------------------------------------------------
__global__ __launch_bounds__(256) void gemm_bt(
    const bf16* __restrict__ A, int lda,
    const bf16* __restrict__ B, int ldb,
    float* __restrict__ C, int ldc,
    const float* __restrict__ bias, int K)
{
  __shared__ __align__(16) bf16 As[128 * 64];
  __shared__ __align__(16) bf16 Bs[128 * 64];
  const int tid = threadIdx.x;
  const int m0 = blockIdx.y * 128, n0 = blockIdx.x * 128;
  const int lane = tid & 63, wave = tid >> 6;
  const int wm = (wave >> 1) * 64, wn = (wave & 1) * 64;
  const int fr = lane & 15, quad = lane >> 4;

  f32x4_t acc[4][4];
  const f32x4_t zero = {0.f, 0.f, 0.f, 0.f};
#pragma unroll
  for (int i = 0; i < 4; ++i)
#pragma unroll
    for (int j = 0; j < 4; ++j) acc[i][j] = zero;

  for (int k0 = 0; k0 < K; k0 += 64) {
    __syncthreads();
#pragma unroll
    for (int j = 0; j < 4; ++j) {
      int c = j * 256 + tid;
      int row = c >> 3, cc = c & 7;    // 8 chunks of 16B per 64-col row
      *(uint4*)(As + row * 64 + cc * 8) =
          *(const uint4*)(A + (size_t)(m0 + row) * lda + k0 + cc * 8);
      *(uint4*)(Bs + row * 64 + cc * 8) =
          *(const uint4*)(B + (size_t)(n0 + row) * ldb + k0 + cc * 8);
    }
    __syncthreads();
#pragma unroll
    for (int kk = 0; kk < 64; kk += 32) {
      bf16x8_t af[4], bfr[4];
#pragma unroll
      for (int mt = 0; mt < 4; ++mt)
        af[mt] = *(const bf16x8_t*)(As + (wm + mt * 16 + fr) * 64 + kk + quad * 8);
#pragma unroll
      for (int nt = 0; nt < 4; ++nt)
        bfr[nt] = *(const bf16x8_t*)(Bs + (wn + nt * 16 + fr) * 64 + kk + quad * 8);
#pragma unroll
      for (int mt = 0; mt < 4; ++mt)
#pragma unroll
        for (int nt = 0; nt < 4; ++nt)
          acc[mt][nt] = __builtin_amdgcn_mfma_f32_16x16x32_bf16(
              af[mt], bfr[nt], acc[mt][nt], 0, 0, 0);
    }
  }

#pragma unroll
  for (int mt = 0; mt < 4; ++mt) {
#pragma unroll
    for (int nt = 0; nt < 4; ++nt) {
      int n = n0 + wn + nt * 16 + fr;
      float bv = bias[n];
#pragma unroll
      for (int r = 0; r < 4; ++r) {
        int m = m0 + wm + mt * 16 + quad * 4 + r;
        C[(size_t)m * ldc + n] = acc[mt][nt][r] + bv;
      }
    }
  }
}

// ---------------------------------------------------------------------------
// Persistent cooperative ENCODER loop. grid = 256 blocks (32 b x 8 i-tiles),
// 256 thr (64 i-lanes x 4 k-groups). One grid.sync per timestep.
// ---------------------------------------------------------------------------
__global__ __launch_bounds__(256) void enc_loop(
    const float* __restrict__ enc_gi, const bf16* __restrict__ Wt,
    const float* __restrict__ bhh, float* __restrict__ enc_out,
    bf16* __restrict__ enc_out_b)
{
  cg::grid_group grid = cg::this_grid();
  __shared__ float hs[Hsz];
  __shared__ float ps[4][3][64];
  const int b = blockIdx.x >> 3, it = blockIdx.x & 7;
  const int tid = threadIdx.x, il = tid & 63, kg = tid >> 6;
  const int i = it * 64 + il;

  for (int k = tid; k < Hsz; k += 256) hs[k] = 0.f;
  __syncthreads();

  for (int t = 0; t < Ssz; ++t) {
    float pr = 0.f, pz = 0.f, pn = 0.f;
    for (int k = kg * 128; k < kg * 128 + 128; ++k) {
      const float hv = hs[k];
      const bf16* w = Wt + (size_t)k * 1536;
      pr += hv * (float)w[i];
      pz += hv * (float)w[Hsz + i];
      pn += hv * (float)w[2 * Hsz + i];
    }
    ps[kg][0][il] = pr; ps[kg][1][il] = pz; ps[kg][2][il] = pn;
    __syncthreads();

    if (tid < 64) {
      float ghr = ps[0][0][il] + ps[1][0][il] + ps[2][0][il] + ps[3][0][il] + bhh[i];
      float ghz = ps[0][1][il] + ps[1][1][il] + ps[2][1][il] + ps[3][1][il] + bhh[Hsz + i];
      float ghn = ps[0][2][il] + ps[1][2][il] + ps[2][2][il] + ps[3][2][il] + bhh[2 * Hsz + i];
      const float* gi = enc_gi + ((size_t)b * Ssz + t) * 1536;
      const float r = sigm(gi[i] + ghr);
      const float z = sigm(gi[Hsz + i] + ghz);
      const float n = tanh_fast(gi[2 * Hsz + i] + r * ghn);
      const float h2 = (1.f - z) * n + z * hs[i];
      const size_t o = ((size_t)b * Ssz + t) * Hsz + i;
      enc_out[o] = h2;
      enc_out_b[o] = __float2bfloat16(h2);
    }
    grid.sync();                       // h(t) now globally visible

    if (t + 1 < Ssz) {                 // reload h for next step
      const float* hsrc = enc_out + ((size_t)b * Ssz + t) * Hsz;
      for (int k = tid; k < Hsz; k += 256) hs[k] = hsrc[k];
      __syncthreads();
    }
  }
}

// ---------------------------------------------------------------------------
// Persistent cooperative DECODER loop. grid = 256 blocks x 256 thr.
// Three phases per timestep separated by grid.sync:
//   P1 (256 blk): gh = h@Whh^T + bhh ; hW = h@Wh^T   (j = blk.jt*256 + tid)
//   P2 ( 32 blk): scores -> softmax -> ctx
//   P3 (256 blk): gi_ctx = ctx@Wihctx^T ; gates ; h(t)
// ---------------------------------------------------------------------------
__global__ __launch_bounds__(256) void dec_loop(
    const float* __restrict__ enc_out, const float* __restrict__ enc_proj,
    const bf16* __restrict__ Wcat_t, const bf16* __restrict__ Wihctx_t,
    const float* __restrict__ dec_gi_y, const float* __restrict__ dbhh,
    const float* __restrict__ attn_v, float* __restrict__ dec_seq,
    bf16* __restrict__ dec_out_b, float* __restrict__ gh_ws,
    float* __restrict__ hW_ws, float* __restrict__ ctx_ws)
{
  cg::grid_group grid = cg::this_grid();
  const int bid = blockIdx.x, tid = threadIdx.x;

  // phase-1 mapping: 32 b x 8 j-tiles of 256
  const int b1 = bid >> 3, jt = bid & 7, j = jt * 256 + tid;
  // phase-3 mapping: 32 b x 8 i-tiles of 64
  const int il = tid & 63, kg = tid >> 6;
  const int i3 = (bid & 7) * 64 + il;

  __shared__ float hs[Hsz];                     // P1
  __shared__ float hw[Hsz], vv[Hsz], sc[Ssz];   // P2
  __shared__ float red[2], red2[2];             // P2
  __shared__ float cs[Hsz];                     // P3
  __shared__ float ps[4][3][64];                // P3

  if (bid < 32)
    for (int k = tid; k < Hsz; k += 256) vv[k] = attn_v[k];
  // (first grid.sync below also acts as a block barrier before vv is read)

  for (int t = 0; t < Tsz; ++t) {
    // ---------------- phase 1 ----------------
    {
      const float* hsrc = (t == 0)
          ? (enc_out + ((size_t)b1 * Ssz + (Ssz - 1)) * Hsz)
          : (dec_seq + ((size_t)b1 * Tsz + (t - 1)) * Hsz);
      for (int k = tid; k < Hsz; k += 256) hs[k] = hsrc[k];
      __syncthreads();
      float p = 0.f;
#pragma unroll 8
      for (int k = 0; k < Hsz; ++k)
        p += hs[k] * (float)Wcat_t[(size_t)k * 2048 + j];
      if (j < 1536) gh_ws[b1 * 1536 + j] = p + dbhh[j];
      else          hW_ws[b1 * Hsz + (j - 1536)] = p;
    }
    grid.sync();

    // ---------------- phase 2 (32 blocks, one per b) ----------------
    if (bid < 32) {
      const int b = bid;
      for (int k = tid; k < Hsz; k += 256) hw[k] = hW_ws[b * Hsz + k];
      __syncthreads();
      const int wv = tid >> 6, lane = tid & 63;
      for (int s = wv; s < Ssz; s += 4) {
        const float* ep = enc_proj + ((size_t)b * Ssz + s) * Hsz;
        float pp = 0.f;
#pragma unroll
        for (int q = 0; q < 8; ++q) {
          int k = q * 64 + lane;
          pp += tanh_fast(hw[k] + ep[k]) * vv[k];
        }
#pragma unroll
        for (int off = 32; off; off >>= 1) pp += __shfl_down(pp, off);
        if (lane == 0) sc[s] = pp;
      }
      __syncthreads();
      if (tid < 128) {
        float v = sc[tid];
#pragma unroll
        for (int off = 32; off; off >>= 1) v = fmaxf(v, __shfl_down(v, off));
        if (lane == 0) red[tid >> 6] = v;
      }
      __syncthreads();
      const float mx = fmaxf(red[0], red[1]);
      if (tid < 128) {
        float e = __expf(sc[tid] - mx);
        sc[tid] = e;
        float v = e;
#pragma unroll
        for (int off = 32; off; off >>= 1) v += __shfl_down(v, off);
        if (lane == 0) red2[tid >> 6] = v;
      }
      __syncthreads();
      const float inv = 1.f / (red2[0] + red2[1]);
      for (int k = tid; k < Hsz; k += 256) {
        float a = 0.f;
        for (int s = 0; s < Ssz; ++s)
          a += sc[s] * enc_out[((size_t)b * Ssz + s) * Hsz + k];
        ctx_ws[b * Hsz + k] = a * inv;
      }
    }
    grid.sync();

    // ---------------- phase 3 ----------------
    {
      for (int k = tid; k < Hsz; k += 256) cs[k] = ctx_ws[b1 * Hsz + k];
      __syncthreads();
      float pr = 0.f, pz = 0.f, pn = 0.f;
      for (int k = kg * 128; k < kg * 128 + 128; ++k) {
        const float c = cs[k];
        const bf16* w = Wihctx_t + (size_t)k * 1536;
        pr += c * (float)w[i3];
        pz += c * (float)w[Hsz + i3];
        pn += c * (float)w[2 * Hsz + i3];
      }
      ps[kg][0][il] = pr; ps[kg][1][il] = pz; ps[kg][2][il] = pn;
      __syncthreads();
      if (tid < 64) {
        const float* giy = dec_gi_y + ((size_t)b1 * Tsz + t) * 1536;
        const float* gh  = gh_ws + b1 * 1536;
        float gir = giy[i3]           + ps[0][0][il] + ps[1][0][il] + ps[2][0][il] + ps[3][0][il];
        float giz = giy[Hsz + i3]     + ps[0][1][il] + ps[1][1][il] + ps[2][1][il] + ps[3][1][il];
        float gin = giy[2 * Hsz + i3] + ps[0][2][il] + ps[1][2][il] + ps[2][2][il] + ps[3][2][il];
        float ghr = gh[i3], ghz = gh[Hsz + i3], ghn = gh[2 * Hsz + i3];
        const float* hsrc = (t == 0)
            ? (enc_out + ((size_t)b1 * Ssz + (Ssz - 1)) * Hsz)
            : (dec_seq + ((size_t)b1 * Tsz + (t - 1)) * Hsz);
        float hp = hsrc[i3];
        const float r = sigm(gir + ghr);
        const float z = sigm(giz + ghz);
        const float n = tanh_fast(gin + r * ghn);
        const float h2 = (1.f - z) * n + z * hp;
        const size_t o = ((size_t)b1 * Tsz + t) * Hsz + i3;
        dec_seq[o] = h2;
        dec_out_b[o] = __float2bfloat16(h2);
      }
    }
    grid.sync();
  }
}

// ---------------------------------------------------------------------------
extern "C" void kernel_launch(void* const* d_in, const int* in_sizes, int n_in,
                              void* d_out, int out_size, void* d_ws, size_t ws_size,
                              hipStream_t stream) {
  const int*   src      = (const int*)d_in[0];
  const int*   tgt      = (const int*)d_in[1];
  const float* emb_src  = (const float*)d_in[2];
  const float* emb_tgt  = (const float*)d_in[3];
  const float* enc_Wih  = (const float*)d_in[4];
  const float* enc_Whh  = (const float*)d_in[5];
  const float* enc_bih  = (const float*)d_in[6];
  const float* enc_bhh  = (const float*)d_in[7];
  const float* dec_Wih  = (const float*)d_in[8];
  const float* dec_Whh  = (const float*)d_in[9];
  const float* dec_bih  = (const float*)d_in[10];
  const float* dec_bhh  = (const float*)d_in[11];
  const float* attn_W   = (const float*)d_in[12];
  const float* attn_b   = (const float*)d_in[13];
  const float* attn_v   = (const float*)d_in[14];
  const float* fc_W     = (const float*)d_in[15];
  const float* fc_b     = (const float*)d_in[16];
  float* out = (float*)d_out;

  char* p = (char*)d_ws;
  auto alloc = [&](size_t n) { char* r = p; p += (n + 255) & ~(size_t)255; return r; };
  float* enc_gi    = (float*)alloc(4096ull * 1536 * 4);  // (B,S,3H) x@Wih^T+bih
  float* dec_gi_y  = (float*)alloc(4096ull * 1536 * 4);  // (B,T,3H) y@WihY^T+bih
  float* enc_out   = (float*)alloc(4096ull * 512 * 4);   // (B,S,H) fp32 h
  float* enc_proj  = (float*)alloc(4096ull * 512 * 4);   // (B,S,H)
  float* dec_seq   = (float*)alloc(4096ull * 512 * 4);   // (B,T,H) fp32 h
  bf16*  enc_out_b = (bf16*)alloc(4096ull * 512 * 2);
  bf16*  dec_out_b = (bf16*)alloc(4096ull * 512 * 2);
  bf16*  xs_b      = (bf16*)alloc(4096ull * 256 * 2);
  bf16*  ys_b      = (bf16*)alloc(4096ull * 256 * 2);
  bf16*  encWhh_t  = (bf16*)alloc(512ull * 1536 * 2);
  bf16*  Wcat_t    = (bf16*)alloc(512ull * 2048 * 2);
  bf16*  Wihctx_t  = (bf16*)alloc(512ull * 1536 * 2);
  bf16*  encWih_b  = (bf16*)alloc(1536ull * 256 * 2);
  bf16*  decWihY_b = (bf16*)alloc(1536ull * 256 * 2);
  bf16*  attnWe_b  = (bf16*)alloc(512ull * 512 * 2);
  bf16*  fcW_b     = (bf16*)alloc(16000ull * 512 * 2);
  float* gh_ws     = (float*)alloc(32ull * 1536 * 4);
  float* hW_ws     = (float*)alloc(32ull * 512 * 4);
  float* ctx_ws    = (float*)alloc(32ull * 512 * 4);

  embed_gather<<<1024, 256, 0, stream>>>(src, tgt, emb_src, emb_tgt, xs_b, ys_b);
  transpose_w<<<10240, 256, 0, stream>>>(enc_Whh, dec_Whh, attn_W, dec_Wih,
                                         encWhh_t, Wcat_t, Wihctx_t);
  pack_weights<<<36096, 256, 0, stream>>>(enc_Wih, dec_Wih, attn_W, fc_W,
                                          encWih_b, decWihY_b, attnWe_b, fcW_b);

  // enc_gi = xs @ enc_Wih^T + bih   (M=4096, N=1536, K=256)
  gemm_bt<<<dim3(12, 32), 256, 0, stream>>>(xs_b, 256, encWih_b, 256,
                                            enc_gi, 1536, enc_bih, 256);
  // dec_gi_y = ys @ dec_Wih[:, :E]^T + bih
  gemm_bt<<<dim3(12, 32), 256, 0, stream>>>(ys_b, 256, decWihY_b, 256,
                                            dec_gi_y, 1536, dec_bih, 256);

  // encoder recurrence: single persistent cooperative kernel
  {
    void* args[] = {(void*)&enc_gi, (void*)&encWhh_t, (void*)&enc_bhh,
                    (void*)&enc_out, (void*)&enc_out_b};
    hipLaunchCooperativeKernel((void*)enc_loop, dim3(256), dim3(256),
                               args, 0, stream);
  }

  // enc_proj = enc_out @ We^T + attn_b  (M=4096, N=512, K=512)
  gemm_bt<<<dim3(4, 32), 256, 0, stream>>>(enc_out_b, 512, attnWe_b, 512,
                                           enc_proj, 512, attn_b, 512);

  // decoder recurrence: single persistent cooperative kernel
  {
    void* args[] = {(void*)&enc_out, (void*)&enc_proj, (void*)&Wcat_t,
                    (void*)&Wihctx_t, (void*)&dec_gi_y, (void*)&dec_bhh,
                    (void*)&attn_v, (void*)&dec_seq, (void*)&dec_out_b,
                    (void*)&gh_ws, (void*)&hW_ws, (void*)&ctx_ws};
    hipLaunchCooperativeKernel((void*)dec_loop, dim3(256), dim3(256),
                               args, 0, stream);
  }

  // logits = dec_out @ fc_W^T + fc_b  (M=4096, N=16000, K=512) -> fp32 out
  gemm_bt<<<dim3(125, 32), 256, 0, stream>>>(dec_out_b, 512, fcW_b, 512,
                                             out, VTsz, fc_b, 512);
}

// Round 2
// 10674.198 us; speedup vs baseline: 2.0169x; 2.0169x over previous
//
#include <hip/hip_runtime.h>
#include <hip/hip_bf16.h>

using bf16 = __hip_bfloat16;
typedef short bf16x8_t __attribute__((ext_vector_type(8)));   // 8 bf16 (4 VGPRs)
typedef float f32x4_t __attribute__((ext_vector_type(4)));

// sizes
#define Bsz 32
#define Ssz 128
#define Tsz 128
#define Esz 256
#define Hsz 512
#define VTsz 16000

#define SCOPE_AGENT __HIP_MEMORY_SCOPE_AGENT

__device__ inline float sigm(float x)      { return 1.f / (1.f + __expf(-x)); }
__device__ inline float tanh_fast(float x) { return 1.f - 2.f / (1.f + __expf(2.f * x)); }

// ---- coherent (device-scope, LLC-resident) scalar exchange helpers --------
__device__ inline float cload(const float* p) {
  return __hip_atomic_load(p, __ATOMIC_RELAXED, SCOPE_AGENT);
}
__device__ inline void cstore(float* p, float v) {
  __hip_atomic_store(p, v, __ATOMIC_RELAXED, SCOPE_AGENT);
}

// ---- relaxed grid barrier: k-th use waits until counter reaches 256*k -----
// No fences/L2 flushes: all cross-block data moves via cload/cstore (sc1,
// coherent at LLC). __syncthreads() before the arrive drains vmcnt(0), so a
// block's coherent stores are globally visible before its add lands.
__device__ inline void gbar(unsigned* cnt, unsigned tgt) {
  __syncthreads();
  if (threadIdx.x == 0) {
    __hip_atomic_fetch_add(cnt, 1u, __ATOMIC_RELAXED, SCOPE_AGENT);
    while (__hip_atomic_load(cnt, __ATOMIC_RELAXED, SCOPE_AGENT) < tgt)
      __builtin_amdgcn_s_sleep(1);
  }
  __syncthreads();
}

__device__ inline unsigned pack2(float x, float y) {
  unsigned short lo = __builtin_bit_cast(unsigned short, __float2bfloat16(x));
  unsigned short hi = __builtin_bit_cast(unsigned short, __float2bfloat16(y));
  return (unsigned)lo | ((unsigned)hi << 16);
}

__device__ inline uint4 f32x8_to_bf16x8(const float* s) {
  float4 a = *(const float4*)s;
  float4 b = *(const float4*)(s + 4);
  uint4 r;
  r.x = pack2(a.x, a.y); r.y = pack2(a.z, a.w);
  r.z = pack2(b.x, b.y); r.w = pack2(b.z, b.w);
  return r;
}

// ---------------------------------------------------------------------------
// Embedding gather + f32->bf16.
// ---------------------------------------------------------------------------
__global__ __launch_bounds__(256) void embed_gather(
    const int* __restrict__ src, const int* __restrict__ tgt,
    const float* __restrict__ es, const float* __restrict__ et,
    bf16* __restrict__ xs_b, bf16* __restrict__ ys_b)
{
  int idx = blockIdx.x * 256 + threadIdx.x;     // 0 .. 262143
  int which = idx >> 17;                        // 131072 chunks per tensor
  int c = idx & 131071;
  int row = c >> 5;                             // 32 chunks per row (E=256)
  int cc = c & 31;
  if (which == 0) {
    int tok = src[row];
    *(uint4*)(xs_b + (size_t)row * Esz + cc * 8) =
        f32x8_to_bf16x8(es + (size_t)tok * Esz + cc * 8);
  } else {
    int tok = tgt[row];
    *(uint4*)(ys_b + (size_t)row * Esz + cc * 8) =
        f32x8_to_bf16x8(et + (size_t)tok * Esz + cc * 8);
  }
}

// ---------------------------------------------------------------------------
// Weight transposes (f32 src -> bf16 dst, k-major for recurrent kernels).
// ---------------------------------------------------------------------------
__global__ __launch_bounds__(256) void transpose_w(
    const float* __restrict__ enc_Whh, const float* __restrict__ dec_Whh,
    const float* __restrict__ attn_W,  const float* __restrict__ dec_Wih,
    bf16* __restrict__ encWhh_t, bf16* __restrict__ Wcat_t, bf16* __restrict__ Wihctx_t)
{
  int idx = blockIdx.x * 256 + threadIdx.x;
  const int N1 = 512 * 1536, N2 = 512 * 2048;
  if (idx < N1) {
    int k = idx / 1536, j = idx % 1536;
    encWhh_t[idx] = __float2bfloat16(enc_Whh[(size_t)j * 512 + k]);
  } else if (idx < N1 + N2) {
    int r = idx - N1;
    int k = r / 2048, j = r % 2048;
    float v = (j < 1536) ? dec_Whh[(size_t)j * 512 + k]
                         : attn_W[(size_t)(j - 1536) * 1024 + k];
    Wcat_t[r] = __float2bfloat16(v);
  } else {
    int r = idx - N1 - N2;
    int k = r / 1536, j = r % 1536;
    Wihctx_t[r] = __float2bfloat16(dec_Wih[(size_t)j * 768 + 256 + k]);
  }
}

// ---------------------------------------------------------------------------
// Pack GEMM B-operands f32 -> bf16 (row-major, packed). Also zeroes the
// grid-barrier state (runs before the persistent loops on every replay).
// ---------------------------------------------------------------------------
__global__ __launch_bounds__(256) void pack_weights(
    const float* __restrict__ enc_Wih, const float* __restrict__ dec_Wih,
    const float* __restrict__ attn_W,  const float* __restrict__ fc_W,
    bf16* __restrict__ encWih_b, bf16* __restrict__ decWihY_b,
    bf16* __restrict__ attnWe_b, bf16* __restrict__ fcW_b,
    unsigned* __restrict__ bar_ws)
{
  if (blockIdx.x == 0 && threadIdx.x < 64) bar_ws[threadIdx.x] = 0u;
  int idx = blockIdx.x * 256 + threadIdx.x;
  const int R1 = 1536 * 256, R2 = 1536 * 256, R3 = 512 * 512;
  if (idx < R1) {
    encWih_b[idx] = __float2bfloat16(enc_Wih[idx]);
  } else if (idx < R1 + R2) {
    int r = idx - R1;
    int row = r >> 8, col = r & 255;
    decWihY_b[r] = __float2bfloat16(dec_Wih[(size_t)row * 768 + col]);
  } else if (idx < R1 + R2 + R3) {
    int r = idx - R1 - R2;
    int row = r >> 9, col = r & 511;
    attnWe_b[r] = __float2bfloat16(attn_W[(size_t)row * 1024 + 512 + col]);
  } else {
    int r = idx - R1 - R2 - R3;
    fcW_b[r] = __float2bfloat16(fc_W[r]);
  }
}

// ---------------------------------------------------------------------------
// MFMA GEMM: C[m,n] = sum_k A[m,k]*B[n,k] + bias[n]. 128x128 tile, BK=64.
// ---------------------------------------------------------------------------
__global__ __launch_bounds__(256) void gemm_bt(
    const bf16* __restrict__ A, int lda,
    const bf16* __restrict__ B, int ldb,
    float* __restrict__ C, int ldc,
    const float* __restrict__ bias, int K)
{
  __shared__ __align__(16) bf16 As[128 * 64];
  __shared__ __align__(16) bf16 Bs[128 * 64];
  const int tid = threadIdx.x;
  const int m0 = blockIdx.y * 128, n0 = blockIdx.x * 128;
  const int lane = tid & 63, wave = tid >> 6;
  const int wm = (wave >> 1) * 64, wn = (wave & 1) * 64;
  const int fr = lane & 15, quad = lane >> 4;

  f32x4_t acc[4][4];
  const f32x4_t zero = {0.f, 0.f, 0.f, 0.f};
#pragma unroll
  for (int i = 0; i < 4; ++i)
#pragma unroll
    for (int j = 0; j < 4; ++j) acc[i][j] = zero;

  for (int k0 = 0; k0 < K; k0 += 64) {
    __syncthreads();
#pragma unroll
    for (int j = 0; j < 4; ++j) {
      int c = j * 256 + tid;
      int row = c >> 3, cc = c & 7;    // 8 chunks of 16B per 64-col row
      *(uint4*)(As + row * 64 + cc * 8) =
          *(const uint4*)(A + (size_t)(m0 + row) * lda + k0 + cc * 8);
      *(uint4*)(Bs + row * 64 + cc * 8) =
          *(const uint4*)(B + (size_t)(n0 + row) * ldb + k0 + cc * 8);
    }
    __syncthreads();
#pragma unroll
    for (int kk = 0; kk < 64; kk += 32) {
      bf16x8_t af[4], bfr[4];
#pragma unroll
      for (int mt = 0; mt < 4; ++mt)
        af[mt] = *(const bf16x8_t*)(As + (wm + mt * 16 + fr) * 64 + kk + quad * 8);
#pragma unroll
      for (int nt = 0; nt < 4; ++nt)
        bfr[nt] = *(const bf16x8_t*)(Bs + (wn + nt * 16 + fr) * 64 + kk + quad * 8);
#pragma unroll
      for (int mt = 0; mt < 4; ++mt)
#pragma unroll
        for (int nt = 0; nt < 4; ++nt)
          acc[mt][nt] = __builtin_amdgcn_mfma_f32_16x16x32_bf16(
              af[mt], bfr[nt], acc[mt][nt], 0, 0, 0);
    }
  }

#pragma unroll
  for (int mt = 0; mt < 4; ++mt) {
#pragma unroll
    for (int nt = 0; nt < 4; ++nt) {
      int n = n0 + wn + nt * 16 + fr;
      float bv = bias[n];
#pragma unroll
      for (int r = 0; r < 4; ++r) {
        int m = m0 + wm + mt * 16 + quad * 4 + r;
        C[(size_t)m * ldc + n] = acc[mt][nt][r] + bv;
      }
    }
  }
}

// ---------------------------------------------------------------------------
// Persistent ENCODER loop. grid = 256 blocks (32 b x 8 i-tiles), 256 thr.
// One relaxed grid barrier per timestep; h-state exchanged via cload/cstore.
// ---------------------------------------------------------------------------
__global__ __launch_bounds__(256) void enc_loop(
    const float* __restrict__ enc_gi, const bf16* __restrict__ Wt,
    const float* __restrict__ bhh, float* __restrict__ enc_out,
    bf16* __restrict__ enc_out_b, unsigned* __restrict__ barc)
{
  __shared__ float hs[Hsz];
  __shared__ float ps[4][3][64];
  const int b = blockIdx.x >> 3, it = blockIdx.x & 7;
  const int tid = threadIdx.x, il = tid & 63, kg = tid >> 6;
  const int i = it * 64 + il;

  for (int k = tid; k < Hsz; k += 256) hs[k] = 0.f;
  __syncthreads();

  unsigned bk = 0;
  for (int t = 0; t < Ssz; ++t) {
    float pr = 0.f, pz = 0.f, pn = 0.f;
    for (int k = kg * 128; k < kg * 128 + 128; ++k) {
      const float hv = hs[k];
      const bf16* w = Wt + (size_t)k * 1536;
      pr += hv * (float)w[i];
      pz += hv * (float)w[Hsz + i];
      pn += hv * (float)w[2 * Hsz + i];
    }
    ps[kg][0][il] = pr; ps[kg][1][il] = pz; ps[kg][2][il] = pn;
    __syncthreads();

    if (tid < 64) {
      float ghr = ps[0][0][il] + ps[1][0][il] + ps[2][0][il] + ps[3][0][il] + bhh[i];
      float ghz = ps[0][1][il] + ps[1][1][il] + ps[2][1][il] + ps[3][1][il] + bhh[Hsz + i];
      float ghn = ps[0][2][il] + ps[1][2][il] + ps[2][2][il] + ps[3][2][il] + bhh[2 * Hsz + i];
      const float* gi = enc_gi + ((size_t)b * Ssz + t) * 1536;
      const float r = sigm(gi[i] + ghr);
      const float z = sigm(gi[Hsz + i] + ghz);
      const float n = tanh_fast(gi[2 * Hsz + i] + r * ghn);
      const float h2 = (1.f - z) * n + z * hs[i];
      const size_t o = ((size_t)b * Ssz + t) * Hsz + i;
      cstore(&enc_out[o], h2);
      enc_out_b[o] = __float2bfloat16(h2);
    }
    gbar(barc, 256u * (++bk));         // h(t) visible at LLC

    if (t + 1 < Ssz) {                 // reload h for next step
      const float* hsrc = enc_out + ((size_t)b * Ssz + t) * Hsz;
      for (int k = tid; k < Hsz; k += 256) hs[k] = cload(hsrc + k);
      __syncthreads();
    }
  }
}

// ---------------------------------------------------------------------------
// Persistent DECODER loop. grid = 256 blocks x 256 thr. Three phases per
// timestep separated by relaxed grid barriers:
//   P1 (256 blk): gh = h@Whh^T + bhh ; hW = h@Wh^T   (j = jt*256 + tid)
//   P2 ( 32 blk): scores -> softmax -> ctx
//   P3 (256 blk): gi_ctx = ctx@Wihctx^T ; gates ; h(t)
// Cross-block data (gh_ws, hW_ws, ctx_ws, dec_seq) via cload/cstore only.
// ---------------------------------------------------------------------------
__global__ __launch_bounds__(256) void dec_loop(
    const float* __restrict__ enc_out, const float* __restrict__ enc_proj,
    const bf16* __restrict__ Wcat_t, const bf16* __restrict__ Wihctx_t,
    const float* __restrict__ dec_gi_y, const float* __restrict__ dbhh,
    const float* __restrict__ attn_v, float* __restrict__ dec_seq,
    bf16* __restrict__ dec_out_b, float* __restrict__ gh_ws,
    float* __restrict__ hW_ws, float* __restrict__ ctx_ws,
    unsigned* __restrict__ barc)
{
  const int bid = blockIdx.x, tid = threadIdx.x;

  // phase-1 mapping: 32 b x 8 j-tiles of 256
  const int b1 = bid >> 3, jt = bid & 7, j = jt * 256 + tid;
  // phase-3 mapping: 32 b x 8 i-tiles of 64
  const int il = tid & 63, kg = tid >> 6;
  const int i3 = (bid & 7) * 64 + il;

  __shared__ float hs[Hsz];                     // P1
  __shared__ float hw[Hsz], vv[Hsz], sc[Ssz];   // P2
  __shared__ float red[2], red2[2];             // P2
  __shared__ float cs[Hsz];                     // P3
  __shared__ float ps[4][3][64];                // P3

  if (bid < 32)
    for (int k = tid; k < Hsz; k += 256) vv[k] = attn_v[k];
  __syncthreads();

  unsigned bk = 0;
  for (int t = 0; t < Tsz; ++t) {
    // ---------------- phase 1 ----------------
    {
      const float* hsrc = (t == 0)
          ? (enc_out + ((size_t)b1 * Ssz + (Ssz - 1)) * Hsz)
          : (dec_seq + ((size_t)b1 * Tsz + (t - 1)) * Hsz);
      for (int k = tid; k < Hsz; k += 256) hs[k] = cload(hsrc + k);
      __syncthreads();
      float p = 0.f;
#pragma unroll 8
      for (int k = 0; k < Hsz; ++k)
        p += hs[k] * (float)Wcat_t[(size_t)k * 2048 + j];
      if (j < 1536) cstore(&gh_ws[b1 * 1536 + j], p + dbhh[j]);
      else          cstore(&hW_ws[b1 * Hsz + (j - 1536)], p);
    }
    gbar(barc, 256u * (++bk));

    // ---------------- phase 2 (32 blocks, one per b) ----------------
    if (bid < 32) {
      const int b = bid;
      for (int k = tid; k < Hsz; k += 256) hw[k] = cload(&hW_ws[b * Hsz + k]);
      __syncthreads();
      const int wv = tid >> 6, lane = tid & 63;
      for (int s = wv; s < Ssz; s += 4) {
        const float* ep = enc_proj + ((size_t)b * Ssz + s) * Hsz;
        float pp = 0.f;
#pragma unroll
        for (int q = 0; q < 8; ++q) {
          int k = q * 64 + lane;
          pp += tanh_fast(hw[k] + ep[k]) * vv[k];
        }
#pragma unroll
        for (int off = 32; off; off >>= 1) pp += __shfl_down(pp, off);
        if (lane == 0) sc[s] = pp;
      }
      __syncthreads();
      if (tid < 128) {
        float v = sc[tid];
#pragma unroll
        for (int off = 32; off; off >>= 1) v = fmaxf(v, __shfl_down(v, off));
        if (lane == 0) red[tid >> 6] = v;
      }
      __syncthreads();
      const float mx = fmaxf(red[0], red[1]);
      if (tid < 128) {
        float e = __expf(sc[tid] - mx);
        sc[tid] = e;
        float v = e;
#pragma unroll
        for (int off = 32; off; off >>= 1) v += __shfl_down(v, off);
        if (lane == 0) red2[tid >> 6] = v;
      }
      __syncthreads();
      const float inv = 1.f / (red2[0] + red2[1]);
      for (int k = tid; k < Hsz; k += 256) {
        float a = 0.f;
        for (int s = 0; s < Ssz; ++s)
          a += sc[s] * enc_out[((size_t)b * Ssz + s) * Hsz + k];
        cstore(&ctx_ws[b * Hsz + k], a * inv);
      }
    }
    gbar(barc, 256u * (++bk));

    // ---------------- phase 3 ----------------
    {
      for (int k = tid; k < Hsz; k += 256) cs[k] = cload(&ctx_ws[b1 * Hsz + k]);
      __syncthreads();
      float pr = 0.f, pz = 0.f, pn = 0.f;
      for (int k = kg * 128; k < kg * 128 + 128; ++k) {
        const float c = cs[k];
        const bf16* w = Wihctx_t + (size_t)k * 1536;
        pr += c * (float)w[i3];
        pz += c * (float)w[Hsz + i3];
        pn += c * (float)w[2 * Hsz + i3];
      }
      ps[kg][0][il] = pr; ps[kg][1][il] = pz; ps[kg][2][il] = pn;
      __syncthreads();
      if (tid < 64) {
        const float* giy = dec_gi_y + ((size_t)b1 * Tsz + t) * 1536;
        float gir = giy[i3]           + ps[0][0][il] + ps[1][0][il] + ps[2][0][il] + ps[3][0][il];
        float giz = giy[Hsz + i3]     + ps[0][1][il] + ps[1][1][il] + ps[2][1][il] + ps[3][1][il];
        float gin = giy[2 * Hsz + i3] + ps[0][2][il] + ps[1][2][il] + ps[2][2][il] + ps[3][2][il];
        float ghr = cload(&gh_ws[b1 * 1536 + i3]);
        float ghz = cload(&gh_ws[b1 * 1536 + Hsz + i3]);
        float ghn = cload(&gh_ws[b1 * 1536 + 2 * Hsz + i3]);
        const float* hsrc = (t == 0)
            ? (enc_out + ((size_t)b1 * Ssz + (Ssz - 1)) * Hsz)
            : (dec_seq + ((size_t)b1 * Tsz + (t - 1)) * Hsz);
        float hp = cload(hsrc + i3);
        const float r = sigm(gir + ghr);
        const float z = sigm(giz + ghz);
        const float n = tanh_fast(gin + r * ghn);
        const float h2 = (1.f - z) * n + z * hp;
        const size_t o = ((size_t)b1 * Tsz + t) * Hsz + i3;
        cstore(&dec_seq[o], h2);
        dec_out_b[o] = __float2bfloat16(h2);
      }
    }
    gbar(barc, 256u * (++bk));
  }
}

// ---------------------------------------------------------------------------
extern "C" void kernel_launch(void* const* d_in, const int* in_sizes, int n_in,
                              void* d_out, int out_size, void* d_ws, size_t ws_size,
                              hipStream_t stream) {
  const int*   src      = (const int*)d_in[0];
  const int*   tgt      = (const int*)d_in[1];
  const float* emb_src  = (const float*)d_in[2];
  const float* emb_tgt  = (const float*)d_in[3];
  const float* enc_Wih  = (const float*)d_in[4];
  const float* enc_Whh  = (const float*)d_in[5];
  const float* enc_bih  = (const float*)d_in[6];
  const float* enc_bhh  = (const float*)d_in[7];
  const float* dec_Wih  = (const float*)d_in[8];
  const float* dec_Whh  = (const float*)d_in[9];
  const float* dec_bih  = (const float*)d_in[10];
  const float* dec_bhh  = (const float*)d_in[11];
  const float* attn_W   = (const float*)d_in[12];
  const float* attn_b   = (const float*)d_in[13];
  const float* attn_v   = (const float*)d_in[14];
  const float* fc_W     = (const float*)d_in[15];
  const float* fc_b     = (const float*)d_in[16];
  float* out = (float*)d_out;

  char* p = (char*)d_ws;
  auto alloc = [&](size_t n) { char* r = p; p += (n + 255) & ~(size_t)255; return r; };
  float* enc_gi    = (float*)alloc(4096ull * 1536 * 4);  // (B,S,3H) x@Wih^T+bih
  float* dec_gi_y  = (float*)alloc(4096ull * 1536 * 4);  // (B,T,3H) y@WihY^T+bih
  float* enc_out   = (float*)alloc(4096ull * 512 * 4);   // (B,S,H) fp32 h
  float* enc_proj  = (float*)alloc(4096ull * 512 * 4);   // (B,S,H)
  float* dec_seq   = (float*)alloc(4096ull * 512 * 4);   // (B,T,H) fp32 h
  bf16*  enc_out_b = (bf16*)alloc(4096ull * 512 * 2);
  bf16*  dec_out_b = (bf16*)alloc(4096ull * 512 * 2);
  bf16*  xs_b      = (bf16*)alloc(4096ull * 256 * 2);
  bf16*  ys_b      = (bf16*)alloc(4096ull * 256 * 2);
  bf16*  encWhh_t  = (bf16*)alloc(512ull * 1536 * 2);
  bf16*  Wcat_t    = (bf16*)alloc(512ull * 2048 * 2);
  bf16*  Wihctx_t  = (bf16*)alloc(512ull * 1536 * 2);
  bf16*  encWih_b  = (bf16*)alloc(1536ull * 256 * 2);
  bf16*  decWihY_b = (bf16*)alloc(1536ull * 256 * 2);
  bf16*  attnWe_b  = (bf16*)alloc(512ull * 512 * 2);
  bf16*  fcW_b     = (bf16*)alloc(16000ull * 512 * 2);
  float* gh_ws     = (float*)alloc(32ull * 1536 * 4);
  float* hW_ws     = (float*)alloc(32ull * 512 * 4);
  float* ctx_ws    = (float*)alloc(32ull * 512 * 4);
  unsigned* bar_ws = (unsigned*)alloc(256);              // [0]=enc cnt, [32]=dec cnt

  embed_gather<<<1024, 256, 0, stream>>>(src, tgt, emb_src, emb_tgt, xs_b, ys_b);
  transpose_w<<<10240, 256, 0, stream>>>(enc_Whh, dec_Whh, attn_W, dec_Wih,
                                         encWhh_t, Wcat_t, Wihctx_t);
  pack_weights<<<36096, 256, 0, stream>>>(enc_Wih, dec_Wih, attn_W, fc_W,
                                          encWih_b, decWihY_b, attnWe_b, fcW_b,
                                          bar_ws);

  // enc_gi = xs @ enc_Wih^T + bih   (M=4096, N=1536, K=256)
  gemm_bt<<<dim3(12, 32), 256, 0, stream>>>(xs_b, 256, encWih_b, 256,
                                            enc_gi, 1536, enc_bih, 256);
  // dec_gi_y = ys @ dec_Wih[:, :E]^T + bih
  gemm_bt<<<dim3(12, 32), 256, 0, stream>>>(ys_b, 256, decWihY_b, 256,
                                            dec_gi_y, 1536, dec_bih, 256);

  // encoder recurrence: persistent cooperative kernel, custom barrier
  {
    unsigned* barc = bar_ws;
    void* args[] = {(void*)&enc_gi, (void*)&encWhh_t, (void*)&enc_bhh,
                    (void*)&enc_out, (void*)&enc_out_b, (void*)&barc};
    hipLaunchCooperativeKernel((void*)enc_loop, dim3(256), dim3(256),
                               args, 0, stream);
  }

  // enc_proj = enc_out @ We^T + attn_b  (M=4096, N=512, K=512)
  gemm_bt<<<dim3(4, 32), 256, 0, stream>>>(enc_out_b, 512, attnWe_b, 512,
                                           enc_proj, 512, attn_b, 512);

  // decoder recurrence: persistent cooperative kernel, custom barrier
  {
    unsigned* barc = bar_ws + 32;
    void* args[] = {(void*)&enc_out, (void*)&enc_proj, (void*)&Wcat_t,
                    (void*)&Wihctx_t, (void*)&dec_gi_y, (void*)&dec_bhh,
                    (void*)&attn_v, (void*)&dec_seq, (void*)&dec_out_b,
                    (void*)&gh_ws, (void*)&hW_ws, (void*)&ctx_ws,
                    (void*)&barc};
    hipLaunchCooperativeKernel((void*)dec_loop, dim3(256), dim3(256),
                               args, 0, stream);
  }

  // logits = dec_out @ fc_W^T + fc_b  (M=4096, N=16000, K=512) -> fp32 out
  gemm_bt<<<dim3(125, 32), 256, 0, stream>>>(dec_out_b, 512, fcW_b, 512,
                                             out, VTsz, fc_b, 512);
}

// Round 3
// 9780.916 us; speedup vs baseline: 2.2011x; 1.0913x over previous
//
#include <hip/hip_runtime.h>
#include <hip/hip_bf16.h>

using bf16 = __hip_bfloat16;
typedef short bf16x8_t __attribute__((ext_vector_type(8)));   // 8 bf16 (4 VGPRs)
typedef float f32x4_t __attribute__((ext_vector_type(4)));

// sizes
#define Bsz 32
#define Ssz 128
#define Tsz 128
#define Esz 256
#define Hsz 512
#define VTsz 16000

#define SCOPE_AGENT __HIP_MEMORY_SCOPE_AGENT

__device__ inline float sigm(float x)      { return 1.f / (1.f + __expf(-x)); }
__device__ inline float tanh_fast(float x) { return 1.f - 2.f / (1.f + __expf(2.f * x)); }

// ---- coherent (device-scope, LLC-resident) scalar exchange helpers --------
__device__ inline float cload(const float* p) {
  return __hip_atomic_load(p, __ATOMIC_RELAXED, SCOPE_AGENT);
}
__device__ inline void cstore(float* p, float v) {
  __hip_atomic_store(p, v, __ATOMIC_RELAXED, SCOPE_AGENT);
}

// ---- flag-array grid barrier (256 blocks) ---------------------------------
// Arrival: block bid STORES epoch to flags[bid] (256 independent addresses,
// fully parallel -- no RMW serialization on one line, unlike fetch_add).
// Poll: wave 0 reads all 256 flags (4/lane) until __all(flag >= epoch).
// Epochs are monotonic; no reset between uses. __syncthreads() before the
// arrive drains vmcnt(0), so the block's coherent (sc1) data stores are
// visible at the LLC before its flag lands.
__device__ inline void gbar(unsigned* flags, unsigned epoch) {
  __syncthreads();
  if (threadIdx.x == 0)
    __hip_atomic_store(&flags[blockIdx.x], epoch, __ATOMIC_RELAXED, SCOPE_AGENT);
  if (threadIdx.x < 64) {
    const int base = (int)threadIdx.x * 4;
    for (;;) {
      unsigned a = __hip_atomic_load(&flags[base + 0], __ATOMIC_RELAXED, SCOPE_AGENT);
      unsigned b = __hip_atomic_load(&flags[base + 1], __ATOMIC_RELAXED, SCOPE_AGENT);
      unsigned c = __hip_atomic_load(&flags[base + 2], __ATOMIC_RELAXED, SCOPE_AGENT);
      unsigned d = __hip_atomic_load(&flags[base + 3], __ATOMIC_RELAXED, SCOPE_AGENT);
      bool ok = (a >= epoch) && (b >= epoch) && (c >= epoch) && (d >= epoch);
      if (__all(ok)) break;
      __builtin_amdgcn_s_sleep(1);
    }
  }
  __syncthreads();
}

__device__ inline unsigned pack2(float x, float y) {
  unsigned short lo = __builtin_bit_cast(unsigned short, __float2bfloat16(x));
  unsigned short hi = __builtin_bit_cast(unsigned short, __float2bfloat16(y));
  return (unsigned)lo | ((unsigned)hi << 16);
}

__device__ inline uint4 f32x8_to_bf16x8(const float* s) {
  float4 a = *(const float4*)s;
  float4 b = *(const float4*)(s + 4);
  uint4 r;
  r.x = pack2(a.x, a.y); r.y = pack2(a.z, a.w);
  r.z = pack2(b.x, b.y); r.w = pack2(b.z, b.w);
  return r;
}

// ---------------------------------------------------------------------------
// Embedding gather + f32->bf16.
// ---------------------------------------------------------------------------
__global__ __launch_bounds__(256) void embed_gather(
    const int* __restrict__ src, const int* __restrict__ tgt,
    const float* __restrict__ es, const float* __restrict__ et,
    bf16* __restrict__ xs_b, bf16* __restrict__ ys_b)
{
  int idx = blockIdx.x * 256 + threadIdx.x;     // 0 .. 262143
  int which = idx >> 17;                        // 131072 chunks per tensor
  int c = idx & 131071;
  int row = c >> 5;                             // 32 chunks per row (E=256)
  int cc = c & 31;
  if (which == 0) {
    int tok = src[row];
    *(uint4*)(xs_b + (size_t)row * Esz + cc * 8) =
        f32x8_to_bf16x8(es + (size_t)tok * Esz + cc * 8);
  } else {
    int tok = tgt[row];
    *(uint4*)(ys_b + (size_t)row * Esz + cc * 8) =
        f32x8_to_bf16x8(et + (size_t)tok * Esz + cc * 8);
  }
}

// ---------------------------------------------------------------------------
// Weight transposes (f32 src -> bf16 dst, k-major for recurrent kernels).
// ---------------------------------------------------------------------------
__global__ __launch_bounds__(256) void transpose_w(
    const float* __restrict__ enc_Whh, const float* __restrict__ dec_Whh,
    const float* __restrict__ attn_W,  const float* __restrict__ dec_Wih,
    bf16* __restrict__ encWhh_t, bf16* __restrict__ Wcat_t, bf16* __restrict__ Wihctx_t)
{
  int idx = blockIdx.x * 256 + threadIdx.x;
  const int N1 = 512 * 1536, N2 = 512 * 2048;
  if (idx < N1) {
    int k = idx / 1536, j = idx % 1536;
    encWhh_t[idx] = __float2bfloat16(enc_Whh[(size_t)j * 512 + k]);
  } else if (idx < N1 + N2) {
    int r = idx - N1;
    int k = r / 2048, j = r % 2048;
    float v = (j < 1536) ? dec_Whh[(size_t)j * 512 + k]
                         : attn_W[(size_t)(j - 1536) * 1024 + k];
    Wcat_t[r] = __float2bfloat16(v);
  } else {
    int r = idx - N1 - N2;
    int k = r / 1536, j = r % 1536;
    Wihctx_t[r] = __float2bfloat16(dec_Wih[(size_t)j * 768 + 256 + k]);
  }
}

// ---------------------------------------------------------------------------
// Pack GEMM B-operands f32 -> bf16 (row-major, packed). Also zeroes the
// grid-barrier flags (runs before the persistent loops on every replay).
// ---------------------------------------------------------------------------
__global__ __launch_bounds__(256) void pack_weights(
    const float* __restrict__ enc_Wih, const float* __restrict__ dec_Wih,
    const float* __restrict__ attn_W,  const float* __restrict__ fc_W,
    bf16* __restrict__ encWih_b, bf16* __restrict__ decWihY_b,
    bf16* __restrict__ attnWe_b, bf16* __restrict__ fcW_b,
    unsigned* __restrict__ bar_ws)
{
  if (blockIdx.x == 0) {
    bar_ws[threadIdx.x] = 0u;          // enc flags [0..255]
    bar_ws[256 + threadIdx.x] = 0u;    // dec flags [256..511]
  }
  int idx = blockIdx.x * 256 + threadIdx.x;
  const int R1 = 1536 * 256, R2 = 1536 * 256, R3 = 512 * 512;
  if (idx < R1) {
    encWih_b[idx] = __float2bfloat16(enc_Wih[idx]);
  } else if (idx < R1 + R2) {
    int r = idx - R1;
    int row = r >> 8, col = r & 255;
    decWihY_b[r] = __float2bfloat16(dec_Wih[(size_t)row * 768 + col]);
  } else if (idx < R1 + R2 + R3) {
    int r = idx - R1 - R2;
    int row = r >> 9, col = r & 511;
    attnWe_b[r] = __float2bfloat16(attn_W[(size_t)row * 1024 + 512 + col]);
  } else {
    int r = idx - R1 - R2 - R3;
    fcW_b[r] = __float2bfloat16(fc_W[r]);
  }
}

// ---------------------------------------------------------------------------
// MFMA GEMM: C[m,n] = sum_k A[m,k]*B[n,k] + bias[n]. 128x128 tile, BK=64.
// ---------------------------------------------------------------------------
__global__ __launch_bounds__(256) void gemm_bt(
    const bf16* __restrict__ A, int lda,
    const bf16* __restrict__ B, int ldb,
    float* __restrict__ C, int ldc,
    const float* __restrict__ bias, int K)
{
  __shared__ __align__(16) bf16 As[128 * 64];
  __shared__ __align__(16) bf16 Bs[128 * 64];
  const int tid = threadIdx.x;
  const int m0 = blockIdx.y * 128, n0 = blockIdx.x * 128;
  const int lane = tid & 63, wave = tid >> 6;
  const int wm = (wave >> 1) * 64, wn = (wave & 1) * 64;
  const int fr = lane & 15, quad = lane >> 4;

  f32x4_t acc[4][4];
  const f32x4_t zero = {0.f, 0.f, 0.f, 0.f};
#pragma unroll
  for (int i = 0; i < 4; ++i)
#pragma unroll
    for (int j = 0; j < 4; ++j) acc[i][j] = zero;

  for (int k0 = 0; k0 < K; k0 += 64) {
    __syncthreads();
#pragma unroll
    for (int j = 0; j < 4; ++j) {
      int c = j * 256 + tid;
      int row = c >> 3, cc = c & 7;    // 8 chunks of 16B per 64-col row
      *(uint4*)(As + row * 64 + cc * 8) =
          *(const uint4*)(A + (size_t)(m0 + row) * lda + k0 + cc * 8);
      *(uint4*)(Bs + row * 64 + cc * 8) =
          *(const uint4*)(B + (size_t)(n0 + row) * ldb + k0 + cc * 8);
    }
    __syncthreads();
#pragma unroll
    for (int kk = 0; kk < 64; kk += 32) {
      bf16x8_t af[4], bfr[4];
#pragma unroll
      for (int mt = 0; mt < 4; ++mt)
        af[mt] = *(const bf16x8_t*)(As + (wm + mt * 16 + fr) * 64 + kk + quad * 8);
#pragma unroll
      for (int nt = 0; nt < 4; ++nt)
        bfr[nt] = *(const bf16x8_t*)(Bs + (wn + nt * 16 + fr) * 64 + kk + quad * 8);
#pragma unroll
      for (int mt = 0; mt < 4; ++mt)
#pragma unroll
        for (int nt = 0; nt < 4; ++nt)
          acc[mt][nt] = __builtin_amdgcn_mfma_f32_16x16x32_bf16(
              af[mt], bfr[nt], acc[mt][nt], 0, 0, 0);
    }
  }

#pragma unroll
  for (int mt = 0; mt < 4; ++mt) {
#pragma unroll
    for (int nt = 0; nt < 4; ++nt) {
      int n = n0 + wn + nt * 16 + fr;
      float bv = bias[n];
#pragma unroll
      for (int r = 0; r < 4; ++r) {
        int m = m0 + wm + mt * 16 + quad * 4 + r;
        C[(size_t)m * ldc + n] = acc[mt][nt][r] + bv;
      }
    }
  }
}

// ---------------------------------------------------------------------------
// Persistent ENCODER loop. grid = 256 blocks (32 b x 8 i-tiles), 256 thr.
// One flag barrier per timestep; h-state exchanged via cload/cstore.
// ---------------------------------------------------------------------------
__global__ __launch_bounds__(256) void enc_loop(
    const float* __restrict__ enc_gi, const bf16* __restrict__ Wt,
    const float* __restrict__ bhh, float* __restrict__ enc_out,
    bf16* __restrict__ enc_out_b, unsigned* __restrict__ barf)
{
  __shared__ float hs[Hsz];
  __shared__ float ps[4][3][64];
  const int b = blockIdx.x >> 3, it = blockIdx.x & 7;
  const int tid = threadIdx.x, il = tid & 63, kg = tid >> 6;
  const int i = it * 64 + il;

  for (int k = tid; k < Hsz; k += 256) hs[k] = 0.f;
  __syncthreads();

  unsigned ep = 0;
  for (int t = 0; t < Ssz; ++t) {
    float pr = 0.f, pz = 0.f, pn = 0.f;
    for (int k = kg * 128; k < kg * 128 + 128; ++k) {
      const float hv = hs[k];
      const bf16* w = Wt + (size_t)k * 1536;
      pr += hv * (float)w[i];
      pz += hv * (float)w[Hsz + i];
      pn += hv * (float)w[2 * Hsz + i];
    }
    ps[kg][0][il] = pr; ps[kg][1][il] = pz; ps[kg][2][il] = pn;
    __syncthreads();

    if (tid < 64) {
      float ghr = ps[0][0][il] + ps[1][0][il] + ps[2][0][il] + ps[3][0][il] + bhh[i];
      float ghz = ps[0][1][il] + ps[1][1][il] + ps[2][1][il] + ps[3][1][il] + bhh[Hsz + i];
      float ghn = ps[0][2][il] + ps[1][2][il] + ps[2][2][il] + ps[3][2][il] + bhh[2 * Hsz + i];
      const float* gi = enc_gi + ((size_t)b * Ssz + t) * 1536;
      const float r = sigm(gi[i] + ghr);
      const float z = sigm(gi[Hsz + i] + ghz);
      const float n = tanh_fast(gi[2 * Hsz + i] + r * ghn);
      const float h2 = (1.f - z) * n + z * hs[i];
      const size_t o = ((size_t)b * Ssz + t) * Hsz + i;
      cstore(&enc_out[o], h2);
      enc_out_b[o] = __float2bfloat16(h2);
    }

    if (t + 1 < Ssz) {                 // last step needs no barrier (kernel end)
      gbar(barf, ++ep);                // h(t) visible at LLC
      const float* hsrc = enc_out + ((size_t)b * Ssz + t) * Hsz;
      for (int k = tid; k < Hsz; k += 256) hs[k] = cload(hsrc + k);
      __syncthreads();
    }
  }
}

// ---------------------------------------------------------------------------
// Persistent DECODER loop. grid = 256 blocks x 256 thr. Three phases per
// timestep separated by flag barriers:
//   P1 (256 blk): gh = h@Whh^T + bhh ; hW = h@Wh^T   (j = jt*256 + tid)
//   P2 ( 32 blk): scores -> softmax -> ctx
//   P3 (256 blk): gi_ctx = ctx@Wihctx^T ; gates ; h(t)
// Cross-block data (gh_ws, hW_ws, ctx_ws, dec_seq) via cload/cstore only.
// ---------------------------------------------------------------------------
__global__ __launch_bounds__(256) void dec_loop(
    const float* __restrict__ enc_out, const float* __restrict__ enc_proj,
    const bf16* __restrict__ Wcat_t, const bf16* __restrict__ Wihctx_t,
    const float* __restrict__ dec_gi_y, const float* __restrict__ dbhh,
    const float* __restrict__ attn_v, float* __restrict__ dec_seq,
    bf16* __restrict__ dec_out_b, float* __restrict__ gh_ws,
    float* __restrict__ hW_ws, float* __restrict__ ctx_ws,
    unsigned* __restrict__ barf)
{
  const int bid = blockIdx.x, tid = threadIdx.x;

  // phase-1 mapping: 32 b x 8 j-tiles of 256
  const int b1 = bid >> 3, jt = bid & 7, j = jt * 256 + tid;
  // phase-3 mapping: 32 b x 8 i-tiles of 64
  const int il = tid & 63, kg = tid >> 6;
  const int i3 = (bid & 7) * 64 + il;

  __shared__ float hs[Hsz];                     // P1
  __shared__ float hw[Hsz], vv[Hsz], sc[Ssz];   // P2
  __shared__ float red[2], red2[2];             // P2
  __shared__ float cs[Hsz];                     // P3
  __shared__ float ps[4][3][64];                // P3

  if (bid < 32)
    for (int k = tid; k < Hsz; k += 256) vv[k] = attn_v[k];
  __syncthreads();

  unsigned ep = 0;
  for (int t = 0; t < Tsz; ++t) {
    // ---------------- phase 1 ----------------
    {
      const float* hsrc = (t == 0)
          ? (enc_out + ((size_t)b1 * Ssz + (Ssz - 1)) * Hsz)
          : (dec_seq + ((size_t)b1 * Tsz + (t - 1)) * Hsz);
      for (int k = tid; k < Hsz; k += 256) hs[k] = cload(hsrc + k);
      __syncthreads();
      float p = 0.f;
#pragma unroll 8
      for (int k = 0; k < Hsz; ++k)
        p += hs[k] * (float)Wcat_t[(size_t)k * 2048 + j];
      if (j < 1536) cstore(&gh_ws[b1 * 1536 + j], p + dbhh[j]);
      else          cstore(&hW_ws[b1 * Hsz + (j - 1536)], p);
    }
    gbar(barf, ++ep);

    // ---------------- phase 2 (32 blocks, one per b) ----------------
    if (bid < 32) {
      const int b = bid;
      for (int k = tid; k < Hsz; k += 256) hw[k] = cload(&hW_ws[b * Hsz + k]);
      __syncthreads();
      const int wv = tid >> 6, lane = tid & 63;
      for (int s = wv; s < Ssz; s += 4) {
        const float* ep_ = enc_proj + ((size_t)b * Ssz + s) * Hsz;
        float pp = 0.f;
#pragma unroll
        for (int q = 0; q < 8; ++q) {
          int k = q * 64 + lane;
          pp += tanh_fast(hw[k] + ep_[k]) * vv[k];
        }
#pragma unroll
        for (int off = 32; off; off >>= 1) pp += __shfl_down(pp, off);
        if (lane == 0) sc[s] = pp;
      }
      __syncthreads();
      if (tid < 128) {
        float v = sc[tid];
#pragma unroll
        for (int off = 32; off; off >>= 1) v = fmaxf(v, __shfl_down(v, off));
        if (lane == 0) red[tid >> 6] = v;
      }
      __syncthreads();
      const float mx = fmaxf(red[0], red[1]);
      if (tid < 128) {
        float e = __expf(sc[tid] - mx);
        sc[tid] = e;
        float v = e;
#pragma unroll
        for (int off = 32; off; off >>= 1) v += __shfl_down(v, off);
        if (lane == 0) red2[tid >> 6] = v;
      }
      __syncthreads();
      const float inv = 1.f / (red2[0] + red2[1]);
      for (int k = tid; k < Hsz; k += 256) {
        float a = 0.f;
        for (int s = 0; s < Ssz; ++s)
          a += sc[s] * enc_out[((size_t)b * Ssz + s) * Hsz + k];
        cstore(&ctx_ws[b * Hsz + k], a * inv);
      }
    }
    gbar(barf, ++ep);

    // ---------------- phase 3 ----------------
    {
      for (int k = tid; k < Hsz; k += 256) cs[k] = cload(&ctx_ws[b1 * Hsz + k]);
      __syncthreads();
      float pr = 0.f, pz = 0.f, pn = 0.f;
      for (int k = kg * 128; k < kg * 128 + 128; ++k) {
        const float c = cs[k];
        const bf16* w = Wihctx_t + (size_t)k * 1536;
        pr += c * (float)w[i3];
        pz += c * (float)w[Hsz + i3];
        pn += c * (float)w[2 * Hsz + i3];
      }
      ps[kg][0][il] = pr; ps[kg][1][il] = pz; ps[kg][2][il] = pn;
      __syncthreads();
      if (tid < 64) {
        const float* giy = dec_gi_y + ((size_t)b1 * Tsz + t) * 1536;
        float gir = giy[i3]           + ps[0][0][il] + ps[1][0][il] + ps[2][0][il] + ps[3][0][il];
        float giz = giy[Hsz + i3]     + ps[0][1][il] + ps[1][1][il] + ps[2][1][il] + ps[3][1][il];
        float gin = giy[2 * Hsz + i3] + ps[0][2][il] + ps[1][2][il] + ps[2][2][il] + ps[3][2][il];
        float ghr = cload(&gh_ws[b1 * 1536 + i3]);
        float ghz = cload(&gh_ws[b1 * 1536 + Hsz + i3]);
        float ghn = cload(&gh_ws[b1 * 1536 + 2 * Hsz + i3]);
        const float* hsrc = (t == 0)
            ? (enc_out + ((size_t)b1 * Ssz + (Ssz - 1)) * Hsz)
            : (dec_seq + ((size_t)b1 * Tsz + (t - 1)) * Hsz);
        float hp = cload(hsrc + i3);
        const float r = sigm(gir + ghr);
        const float z = sigm(giz + ghz);
        const float n = tanh_fast(gin + r * ghn);
        const float h2 = (1.f - z) * n + z * hp;
        const size_t o = ((size_t)b1 * Tsz + t) * Hsz + i3;
        cstore(&dec_seq[o], h2);
        dec_out_b[o] = __float2bfloat16(h2);
      }
    }
    if (t + 1 < Tsz) gbar(barf, ++ep);  // last step: kernel end provides visibility
  }
}

// ---------------------------------------------------------------------------
extern "C" void kernel_launch(void* const* d_in, const int* in_sizes, int n_in,
                              void* d_out, int out_size, void* d_ws, size_t ws_size,
                              hipStream_t stream) {
  const int*   src      = (const int*)d_in[0];
  const int*   tgt      = (const int*)d_in[1];
  const float* emb_src  = (const float*)d_in[2];
  const float* emb_tgt  = (const float*)d_in[3];
  const float* enc_Wih  = (const float*)d_in[4];
  const float* enc_Whh  = (const float*)d_in[5];
  const float* enc_bih  = (const float*)d_in[6];
  const float* enc_bhh  = (const float*)d_in[7];
  const float* dec_Wih  = (const float*)d_in[8];
  const float* dec_Whh  = (const float*)d_in[9];
  const float* dec_bih  = (const float*)d_in[10];
  const float* dec_bhh  = (const float*)d_in[11];
  const float* attn_W   = (const float*)d_in[12];
  const float* attn_b   = (const float*)d_in[13];
  const float* attn_v   = (const float*)d_in[14];
  const float* fc_W     = (const float*)d_in[15];
  const float* fc_b     = (const float*)d_in[16];
  float* out = (float*)d_out;

  char* p = (char*)d_ws;
  auto alloc = [&](size_t n) { char* r = p; p += (n + 255) & ~(size_t)255; return r; };
  float* enc_gi    = (float*)alloc(4096ull * 1536 * 4);  // (B,S,3H) x@Wih^T+bih
  float* dec_gi_y  = (float*)alloc(4096ull * 1536 * 4);  // (B,T,3H) y@WihY^T+bih
  float* enc_out   = (float*)alloc(4096ull * 512 * 4);   // (B,S,H) fp32 h
  float* enc_proj  = (float*)alloc(4096ull * 512 * 4);   // (B,S,H)
  float* dec_seq   = (float*)alloc(4096ull * 512 * 4);   // (B,T,H) fp32 h
  bf16*  enc_out_b = (bf16*)alloc(4096ull * 512 * 2);
  bf16*  dec_out_b = (bf16*)alloc(4096ull * 512 * 2);
  bf16*  xs_b      = (bf16*)alloc(4096ull * 256 * 2);
  bf16*  ys_b      = (bf16*)alloc(4096ull * 256 * 2);
  bf16*  encWhh_t  = (bf16*)alloc(512ull * 1536 * 2);
  bf16*  Wcat_t    = (bf16*)alloc(512ull * 2048 * 2);
  bf16*  Wihctx_t  = (bf16*)alloc(512ull * 1536 * 2);
  bf16*  encWih_b  = (bf16*)alloc(1536ull * 256 * 2);
  bf16*  decWihY_b = (bf16*)alloc(1536ull * 256 * 2);
  bf16*  attnWe_b  = (bf16*)alloc(512ull * 512 * 2);
  bf16*  fcW_b     = (bf16*)alloc(16000ull * 512 * 2);
  float* gh_ws     = (float*)alloc(32ull * 1536 * 4);
  float* hW_ws     = (float*)alloc(32ull * 512 * 4);
  float* ctx_ws    = (float*)alloc(32ull * 512 * 4);
  unsigned* bar_ws = (unsigned*)alloc(512 * 4);          // [0..255]=enc, [256..511]=dec

  embed_gather<<<1024, 256, 0, stream>>>(src, tgt, emb_src, emb_tgt, xs_b, ys_b);
  transpose_w<<<10240, 256, 0, stream>>>(enc_Whh, dec_Whh, attn_W, dec_Wih,
                                         encWhh_t, Wcat_t, Wihctx_t);
  pack_weights<<<36096, 256, 0, stream>>>(enc_Wih, dec_Wih, attn_W, fc_W,
                                          encWih_b, decWihY_b, attnWe_b, fcW_b,
                                          bar_ws);

  // enc_gi = xs @ enc_Wih^T + bih   (M=4096, N=1536, K=256)
  gemm_bt<<<dim3(12, 32), 256, 0, stream>>>(xs_b, 256, encWih_b, 256,
                                            enc_gi, 1536, enc_bih, 256);
  // dec_gi_y = ys @ dec_Wih[:, :E]^T + bih
  gemm_bt<<<dim3(12, 32), 256, 0, stream>>>(ys_b, 256, decWihY_b, 256,
                                            dec_gi_y, 1536, dec_bih, 256);

  // encoder recurrence: persistent cooperative kernel, flag barrier
  {
    unsigned* barf = bar_ws;
    void* args[] = {(void*)&enc_gi, (void*)&encWhh_t, (void*)&enc_bhh,
                    (void*)&enc_out, (void*)&enc_out_b, (void*)&barf};
    hipLaunchCooperativeKernel((void*)enc_loop, dim3(256), dim3(256),
                               args, 0, stream);
  }

  // enc_proj = enc_out @ We^T + attn_b  (M=4096, N=512, K=512)
  gemm_bt<<<dim3(4, 32), 256, 0, stream>>>(enc_out_b, 512, attnWe_b, 512,
                                           enc_proj, 512, attn_b, 512);

  // decoder recurrence: persistent cooperative kernel, flag barrier
  {
    unsigned* barf = bar_ws + 256;
    void* args[] = {(void*)&enc_out, (void*)&enc_proj, (void*)&Wcat_t,
                    (void*)&Wihctx_t, (void*)&dec_gi_y, (void*)&dec_bhh,
                    (void*)&attn_v, (void*)&dec_seq, (void*)&dec_out_b,
                    (void*)&gh_ws, (void*)&hW_ws, (void*)&ctx_ws,
                    (void*)&barf};
    hipLaunchCooperativeKernel((void*)dec_loop, dim3(256), dim3(256),
                               args, 0, stream);
  }

  // logits = dec_out @ fc_W^T + fc_b  (M=4096, N=16000, K=512) -> fp32 out
  gemm_bt<<<dim3(125, 32), 256, 0, stream>>>(dec_out_b, 512, fcW_b, 512,
                                             out, VTsz, fc_b, 512);
}

// Round 5
// 6751.411 us; speedup vs baseline: 3.1888x; 1.4487x over previous
//
#include <hip/hip_runtime.h>
#include <hip/hip_bf16.h>

using bf16 = __hip_bfloat16;
typedef short bf16x8_t __attribute__((ext_vector_type(8)));   // 8 bf16 (4 VGPRs)
typedef float f32x4_t __attribute__((ext_vector_type(4)));

// sizes
#define Bsz 32
#define Ssz 128
#define Tsz 128
#define Esz 256
#define Hsz 512
#define VTsz 16000

#define SCOPE_AGENT __HIP_MEMORY_SCOPE_AGENT

__device__ inline float sigm(float x)      { return 1.f / (1.f + __expf(-x)); }
__device__ inline float tanh_fast(float x) { return 1.f - 2.f / (1.f + __expf(2.f * x)); }

// ---- coherent (device-scope, LLC-resident) scalar exchange helpers --------
__device__ inline float cload(const float* p) {
  return __hip_atomic_load(p, __ATOMIC_RELAXED, SCOPE_AGENT);
}
__device__ inline void cstore(float* p, float v) {
  __hip_atomic_store(p, v, __ATOMIC_RELAXED, SCOPE_AGENT);
}

// ---- two-level flag barrier for 256 blocks --------------------------------
// Region layout (word offsets in R, region = 1280 words):
//   [0..255]       per-block arrival flags (block bid stores epoch)
//   [256 + g*64]   group flags, g in 0..15 (256B apart -> distinct lines)
// Flow: block stores R[bid]; 16 leaders (bid%16==0) each poll their group's
// 16 arrival flags (ONE 64B line, single reader) and store the group flag;
// every block's wave 0 then polls the 16 spread group-flag lines (16 loads
// per block per round, ~4k total over 16 lines -- ~16x less than a flat
// 256-flag poll, one less serial LLC hop than a root/release fan-out).
// Visibility: __syncthreads() drains each wave's vmcnt(0), so a block's sc1
// data stores are at the LLC before its arrival-flag store issues; the
// leader/group-flag observation chain preserves that transitively.
// Epochs are monotonic; no reset between uses (pack_weights zeroes once
// per replay, before the persistent kernels run).
__device__ inline void gbar(unsigned* R, unsigned epoch) {
  __syncthreads();
  const int bid = blockIdx.x, tid = threadIdx.x;
  if (tid == 0)
    __hip_atomic_store(&R[bid], epoch, __ATOMIC_RELAXED, SCOPE_AGENT);
  if ((bid & 15) == 0 && tid < 64) {          // group leader, wave 0
    const int g = bid >> 4;
    for (;;) {
      bool ok = true;
      if (tid < 16)
        ok = __hip_atomic_load(&R[g * 16 + tid], __ATOMIC_RELAXED, SCOPE_AGENT) >= epoch;
      if (__all(ok)) break;
      __builtin_amdgcn_s_sleep(1);
    }
    if (tid == 0)
      __hip_atomic_store(&R[256 + g * 64], epoch, __ATOMIC_RELAXED, SCOPE_AGENT);
  }
  if (tid < 64) {                             // all blocks: poll group flags
    for (;;) {
      bool ok = true;
      if (tid < 16)
        ok = __hip_atomic_load(&R[256 + tid * 64], __ATOMIC_RELAXED, SCOPE_AGENT) >= epoch;
      if (__all(ok)) break;
      __builtin_amdgcn_s_sleep(1);
    }
  }
  __syncthreads();
}

__device__ inline unsigned pack2(float x, float y) {
  unsigned short lo = __builtin_bit_cast(unsigned short, __float2bfloat16(x));
  unsigned short hi = __builtin_bit_cast(unsigned short, __float2bfloat16(y));
  return (unsigned)lo | ((unsigned)hi << 16);
}

__device__ inline uint4 f32x8_to_bf16x8(const float* s) {
  float4 a = *(const float4*)s;
  float4 b = *(const float4*)(s + 4);
  uint4 r;
  r.x = pack2(a.x, a.y); r.y = pack2(a.z, a.w);
  r.z = pack2(b.x, b.y); r.w = pack2(b.z, b.w);
  return r;
}

// ---------------------------------------------------------------------------
// Embedding gather + f32->bf16.
// ---------------------------------------------------------------------------
__global__ __launch_bounds__(256) void embed_gather(
    const int* __restrict__ src, const int* __restrict__ tgt,
    const float* __restrict__ es, const float* __restrict__ et,
    bf16* __restrict__ xs_b, bf16* __restrict__ ys_b)
{
  int idx = blockIdx.x * 256 + threadIdx.x;     // 0 .. 262143
  int which = idx >> 17;                        // 131072 chunks per tensor
  int c = idx & 131071;
  int row = c >> 5;                             // 32 chunks per row (E=256)
  int cc = c & 31;
  if (which == 0) {
    int tok = src[row];
    *(uint4*)(xs_b + (size_t)row * Esz + cc * 8) =
        f32x8_to_bf16x8(es + (size_t)tok * Esz + cc * 8);
  } else {
    int tok = tgt[row];
    *(uint4*)(ys_b + (size_t)row * Esz + cc * 8) =
        f32x8_to_bf16x8(et + (size_t)tok * Esz + cc * 8);
  }
}

// ---------------------------------------------------------------------------
// Weight transposes (f32 src -> bf16 dst, k-major for recurrent kernels).
// ---------------------------------------------------------------------------
__global__ __launch_bounds__(256) void transpose_w(
    const float* __restrict__ enc_Whh, const float* __restrict__ dec_Whh,
    const float* __restrict__ attn_W,  const float* __restrict__ dec_Wih,
    bf16* __restrict__ encWhh_t, bf16* __restrict__ Wcat_t, bf16* __restrict__ Wihctx_t)
{
  int idx = blockIdx.x * 256 + threadIdx.x;
  const int N1 = 512 * 1536, N2 = 512 * 2048;
  if (idx < N1) {
    int k = idx / 1536, j = idx % 1536;
    encWhh_t[idx] = __float2bfloat16(enc_Whh[(size_t)j * 512 + k]);
  } else if (idx < N1 + N2) {
    int r = idx - N1;
    int k = r / 2048, j = r % 2048;
    float v = (j < 1536) ? dec_Whh[(size_t)j * 512 + k]
                         : attn_W[(size_t)(j - 1536) * 1024 + k];
    Wcat_t[r] = __float2bfloat16(v);
  } else {
    int r = idx - N1 - N2;
    int k = r / 1536, j = r % 1536;
    Wihctx_t[r] = __float2bfloat16(dec_Wih[(size_t)j * 768 + 256 + k]);
  }
}

// ---------------------------------------------------------------------------
// Pack GEMM B-operands f32 -> bf16 (row-major, packed). Also zeroes the
// grid-barrier state (runs before the persistent loops on every replay).
// ---------------------------------------------------------------------------
__global__ __launch_bounds__(256) void pack_weights(
    const float* __restrict__ enc_Wih, const float* __restrict__ dec_Wih,
    const float* __restrict__ attn_W,  const float* __restrict__ fc_W,
    bf16* __restrict__ encWih_b, bf16* __restrict__ decWihY_b,
    bf16* __restrict__ attnWe_b, bf16* __restrict__ fcW_b,
    unsigned* __restrict__ bar_ws)
{
  int idx = blockIdx.x * 256 + threadIdx.x;
  if (idx < 4096) bar_ws[idx] = 0u;   // enc region [0..1279], dec [2048..3327]
  const int R1 = 1536 * 256, R2 = 1536 * 256, R3 = 512 * 512;
  if (idx < R1) {
    encWih_b[idx] = __float2bfloat16(enc_Wih[idx]);
  } else if (idx < R1 + R2) {
    int r = idx - R1;
    int row = r >> 8, col = r & 255;
    decWihY_b[r] = __float2bfloat16(dec_Wih[(size_t)row * 768 + col]);
  } else if (idx < R1 + R2 + R3) {
    int r = idx - R1 - R2;
    int row = r >> 9, col = r & 511;
    attnWe_b[r] = __float2bfloat16(attn_W[(size_t)row * 1024 + 512 + col]);
  } else {
    int r = idx - R1 - R2 - R3;
    fcW_b[r] = __float2bfloat16(fc_W[r]);
  }
}

// ---------------------------------------------------------------------------
// MFMA GEMM: C[m,n] = sum_k A[m,k]*B[n,k] + bias[n]. 128x128 tile, BK=64.
// ---------------------------------------------------------------------------
__global__ __launch_bounds__(256) void gemm_bt(
    const bf16* __restrict__ A, int lda,
    const bf16* __restrict__ B, int ldb,
    float* __restrict__ C, int ldc,
    const float* __restrict__ bias, int K)
{
  __shared__ __align__(16) bf16 As[128 * 64];
  __shared__ __align__(16) bf16 Bs[128 * 64];
  const int tid = threadIdx.x;
  const int m0 = blockIdx.y * 128, n0 = blockIdx.x * 128;
  const int lane = tid & 63, wave = tid >> 6;
  const int wm = (wave >> 1) * 64, wn = (wave & 1) * 64;
  const int fr = lane & 15, quad = lane >> 4;

  f32x4_t acc[4][4];
  const f32x4_t zero = {0.f, 0.f, 0.f, 0.f};
#pragma unroll
  for (int i = 0; i < 4; ++i)
#pragma unroll
    for (int j = 0; j < 4; ++j) acc[i][j] = zero;

  for (int k0 = 0; k0 < K; k0 += 64) {
    __syncthreads();
#pragma unroll
    for (int j = 0; j < 4; ++j) {
      int c = j * 256 + tid;
      int row = c >> 3, cc = c & 7;    // 8 chunks of 16B per 64-col row
      *(uint4*)(As + row * 64 + cc * 8) =
          *(const uint4*)(A + (size_t)(m0 + row) * lda + k0 + cc * 8);
      *(uint4*)(Bs + row * 64 + cc * 8) =
          *(const uint4*)(B + (size_t)(n0 + row) * ldb + k0 + cc * 8);
    }
    __syncthreads();
#pragma unroll
    for (int kk = 0; kk < 64; kk += 32) {
      bf16x8_t af[4], bfr[4];
#pragma unroll
      for (int mt = 0; mt < 4; ++mt)
        af[mt] = *(const bf16x8_t*)(As + (wm + mt * 16 + fr) * 64 + kk + quad * 8);
#pragma unroll
      for (int nt = 0; nt < 4; ++nt)
        bfr[nt] = *(const bf16x8_t*)(Bs + (wn + nt * 16 + fr) * 64 + kk + quad * 8);
#pragma unroll
      for (int mt = 0; mt < 4; ++mt)
#pragma unroll
        for (int nt = 0; nt < 4; ++nt)
          acc[mt][nt] = __builtin_amdgcn_mfma_f32_16x16x32_bf16(
              af[mt], bfr[nt], acc[mt][nt], 0, 0, 0);
    }
  }

#pragma unroll
  for (int mt = 0; mt < 4; ++mt) {
#pragma unroll
    for (int nt = 0; nt < 4; ++nt) {
      int n = n0 + wn + nt * 16 + fr;
      float bv = bias[n];
#pragma unroll
      for (int r = 0; r < 4; ++r) {
        int m = m0 + wm + mt * 16 + quad * 4 + r;
        C[(size_t)m * ldc + n] = acc[mt][nt][r] + bv;
      }
    }
  }
}

// ---------------------------------------------------------------------------
// Persistent ENCODER loop. grid = 256 blocks (32 b x 8 i-tiles), 512 thr
// (64 i-lanes x 8 k-groups). One barrier per timestep.
// ---------------------------------------------------------------------------
__global__ __launch_bounds__(512) void enc_loop(
    const float* __restrict__ enc_gi, const bf16* __restrict__ Wt,
    const float* __restrict__ bhh, float* __restrict__ enc_out,
    bf16* __restrict__ enc_out_b, unsigned* __restrict__ barf)
{
  __shared__ float hs[Hsz];
  __shared__ float ps[8][3][64];
  const int b = blockIdx.x >> 3, it = blockIdx.x & 7;
  const int tid = threadIdx.x, il = tid & 63, kg = tid >> 6;   // kg 0..7
  const int i = it * 64 + il;

  for (int k = tid; k < Hsz; k += 512) hs[k] = 0.f;
  __syncthreads();

  unsigned epoch = 0;
  for (int t = 0; t < Ssz; ++t) {
    float pr = 0.f, pz = 0.f, pn = 0.f;
#pragma unroll 8
    for (int k = kg * 64; k < kg * 64 + 64; ++k) {
      const float hv = hs[k];
      const bf16* w = Wt + (size_t)k * 1536;
      pr += hv * (float)w[i];
      pz += hv * (float)w[Hsz + i];
      pn += hv * (float)w[2 * Hsz + i];
    }
    ps[kg][0][il] = pr; ps[kg][1][il] = pz; ps[kg][2][il] = pn;
    __syncthreads();

    if (tid < 64) {
      float ghr = 0.f, ghz = 0.f, ghn = 0.f;
#pragma unroll
      for (int g = 0; g < 8; ++g) {
        ghr += ps[g][0][il]; ghz += ps[g][1][il]; ghn += ps[g][2][il];
      }
      ghr += bhh[i]; ghz += bhh[Hsz + i]; ghn += bhh[2 * Hsz + i];
      const float* gi = enc_gi + ((size_t)b * Ssz + t) * 1536;
      const float r = sigm(gi[i] + ghr);
      const float z = sigm(gi[Hsz + i] + ghz);
      const float n = tanh_fast(gi[2 * Hsz + i] + r * ghn);
      const float h2 = (1.f - z) * n + z * hs[i];
      const size_t o = ((size_t)b * Ssz + t) * Hsz + i;
      cstore(&enc_out[o], h2);
      enc_out_b[o] = __float2bfloat16(h2);
    }

    if (t + 1 < Ssz) {                 // last step: kernel end provides visibility
      gbar(barf, ++epoch);
      const float* hsrc = enc_out + ((size_t)b * Ssz + t) * Hsz;
      for (int k = tid; k < Hsz; k += 512) hs[k] = cload(hsrc + k);
      __syncthreads();
    }
  }
}

// ---------------------------------------------------------------------------
// Persistent DECODER loop. grid = 256 blocks x 512 thr. TWO phases per step:
//   P1  (all blocks): gh = h@Whh^T + bhh ; hW = h@Wh^T  (k-split x2, j=jt*256+jl)
//   --- barrier ---
//   P23 (all blocks): scores -> softmax -> ctx (kept in LDS; each of the 8
//        blocks of a batch computes identical values -> bit-identical), then
//        gi_ctx = ctx@Wihctx^T ; gates ; h(t).  NO barrier between P2 and P3.
//   --- barrier (h(t) visible for next P1) ---
// Cross-block data (gh_ws, hW_ws, dec_seq) via cload/cstore only.
// ---------------------------------------------------------------------------
__global__ __launch_bounds__(512) void dec_loop(
    const float* __restrict__ enc_out, const float* __restrict__ enc_proj,
    const bf16* __restrict__ Wcat_t, const bf16* __restrict__ Wihctx_t,
    const float* __restrict__ dec_gi_y, const float* __restrict__ dbhh,
    const float* __restrict__ attn_v, float* __restrict__ dec_seq,
    bf16* __restrict__ dec_out_b, float* __restrict__ gh_ws,
    float* __restrict__ hW_ws, unsigned* __restrict__ barf)
{
  const int bid = blockIdx.x, tid = threadIdx.x;
  const int b1 = bid >> 3;
  // P1 mapping: j = (bid&7)*256 + (tid&255), k-half = tid>>8
  const int jl = tid & 255, kh = tid >> 8;
  const int j = (bid & 7) * 256 + jl;
  // P3 mapping: i3 = (bid&7)*64 + (tid&63), k-group = tid>>6
  const int il = tid & 63, kg = tid >> 6;
  const int i3 = (bid & 7) * 64 + il;

  __shared__ float hs[Hsz];                     // P1 h state
  __shared__ float ps1[2][256];                 // P1 partials
  __shared__ float hw[Hsz], vv[Hsz], sc[Ssz];   // P2
  __shared__ float red[2], red2[2];             // P2
  __shared__ float cs[Hsz];                     // ctx (stays in LDS)
  __shared__ float ps[8][3][64];                // P3 partials

  for (int k = tid; k < Hsz; k += 512) vv[k] = attn_v[k];
  __syncthreads();

  unsigned epoch = 0;
  for (int t = 0; t < Tsz; ++t) {
    // ---------------- phase 1 ----------------
    {
      const float* hsrc = (t == 0)
          ? (enc_out + ((size_t)b1 * Ssz + (Ssz - 1)) * Hsz)
          : (dec_seq + ((size_t)b1 * Tsz + (t - 1)) * Hsz);
      for (int k = tid; k < Hsz; k += 512) hs[k] = cload(hsrc + k);
      __syncthreads();
      float p = 0.f;
#pragma unroll 16
      for (int k = kh * 256; k < kh * 256 + 256; ++k)
        p += hs[k] * (float)Wcat_t[(size_t)k * 2048 + j];
      ps1[kh][jl] = p;
      __syncthreads();
      if (tid < 256) {
        float s = ps1[0][jl] + ps1[1][jl];
        if (j < 1536) cstore(&gh_ws[b1 * 1536 + j], s + dbhh[j]);
        else          cstore(&hW_ws[b1 * Hsz + (j - 1536)], s);
      }
    }
    gbar(barf, ++epoch);

    // ---------------- phase 2 (redundant per 8 blocks, ctx -> LDS) --------
    {
      for (int k = tid; k < Hsz; k += 512) hw[k] = cload(&hW_ws[b1 * Hsz + k]);
      __syncthreads();
      const int wv = tid >> 6;                  // 8 waves, 16 s each
      for (int s = wv; s < Ssz; s += 8) {
        const float* epj = enc_proj + ((size_t)b1 * Ssz + s) * Hsz;
        float pp = 0.f;
#pragma unroll
        for (int q = 0; q < 8; ++q) {
          int k = q * 64 + il;
          pp += tanh_fast(hw[k] + epj[k]) * vv[k];
        }
#pragma unroll
        for (int off = 32; off; off >>= 1) pp += __shfl_down(pp, off);
        if (il == 0) sc[s] = pp;
      }
      __syncthreads();
      if (tid < 128) {
        float v = sc[tid];
#pragma unroll
        for (int off = 32; off; off >>= 1) v = fmaxf(v, __shfl_down(v, off));
        if (il == 0) red[tid >> 6] = v;
      }
      __syncthreads();
      const float mx = fmaxf(red[0], red[1]);
      if (tid < 128) {
        float e = __expf(sc[tid] - mx);
        sc[tid] = e;
        float v = e;
#pragma unroll
        for (int off = 32; off; off >>= 1) v += __shfl_down(v, off);
        if (il == 0) red2[tid >> 6] = v;
      }
      __syncthreads();
      const float inv = 1.f / (red2[0] + red2[1]);
      for (int k = tid; k < Hsz; k += 512) {
        float a = 0.f;
#pragma unroll 8
        for (int s = 0; s < Ssz; ++s)
          a += sc[s] * enc_out[((size_t)b1 * Ssz + s) * Hsz + k];
        cs[k] = a * inv;
      }
      __syncthreads();
    }

    // ---------------- phase 3 (same block, no barrier needed) -------------
    {
      float pr = 0.f, pz = 0.f, pn = 0.f;
#pragma unroll 8
      for (int k = kg * 64; k < kg * 64 + 64; ++k) {
        const float c = cs[k];
        const bf16* w = Wihctx_t + (size_t)k * 1536;
        pr += c * (float)w[i3];
        pz += c * (float)w[Hsz + i3];
        pn += c * (float)w[2 * Hsz + i3];
      }
      ps[kg][0][il] = pr; ps[kg][1][il] = pz; ps[kg][2][il] = pn;
      __syncthreads();
      if (tid < 64) {
        float sr = 0.f, sz = 0.f, sn = 0.f;
#pragma unroll
        for (int g = 0; g < 8; ++g) {
          sr += ps[g][0][il]; sz += ps[g][1][il]; sn += ps[g][2][il];
        }
        const float* giy = dec_gi_y + ((size_t)b1 * Tsz + t) * 1536;
        float gir = giy[i3] + sr;
        float giz = giy[Hsz + i3] + sz;
        float gin = giy[2 * Hsz + i3] + sn;
        float ghr = cload(&gh_ws[b1 * 1536 + i3]);
        float ghz = cload(&gh_ws[b1 * 1536 + Hsz + i3]);
        float ghn = cload(&gh_ws[b1 * 1536 + 2 * Hsz + i3]);
        const float* hsrc = (t == 0)
            ? (enc_out + ((size_t)b1 * Ssz + (Ssz - 1)) * Hsz)
            : (dec_seq + ((size_t)b1 * Tsz + (t - 1)) * Hsz);
        float hp = cload(hsrc + i3);
        const float r = sigm(gir + ghr);
        const float z = sigm(giz + ghz);
        const float n = tanh_fast(gin + r * ghn);
        const float h2 = (1.f - z) * n + z * hp;
        const size_t o = ((size_t)b1 * Tsz + t) * Hsz + i3;
        cstore(&dec_seq[o], h2);
        dec_out_b[o] = __float2bfloat16(h2);
      }
    }
    if (t + 1 < Tsz) gbar(barf, ++epoch);  // last step: kernel end flushes
  }
}

// ---------------------------------------------------------------------------
extern "C" void kernel_launch(void* const* d_in, const int* in_sizes, int n_in,
                              void* d_out, int out_size, void* d_ws, size_t ws_size,
                              hipStream_t stream) {
  const int*   src      = (const int*)d_in[0];
  const int*   tgt      = (const int*)d_in[1];
  const float* emb_src  = (const float*)d_in[2];
  const float* emb_tgt  = (const float*)d_in[3];
  const float* enc_Wih  = (const float*)d_in[4];
  const float* enc_Whh  = (const float*)d_in[5];
  const float* enc_bih  = (const float*)d_in[6];
  const float* enc_bhh  = (const float*)d_in[7];
  const float* dec_Wih  = (const float*)d_in[8];
  const float* dec_Whh  = (const float*)d_in[9];
  const float* dec_bih  = (const float*)d_in[10];
  const float* dec_bhh  = (const float*)d_in[11];
  const float* attn_W   = (const float*)d_in[12];
  const float* attn_b   = (const float*)d_in[13];
  const float* attn_v   = (const float*)d_in[14];
  const float* fc_W     = (const float*)d_in[15];
  const float* fc_b     = (const float*)d_in[16];
  float* out = (float*)d_out;

  char* p = (char*)d_ws;
  auto alloc = [&](size_t n) { char* r = p; p += (n + 255) & ~(size_t)255; return r; };
  float* enc_gi    = (float*)alloc(4096ull * 1536 * 4);  // (B,S,3H) x@Wih^T+bih
  float* dec_gi_y  = (float*)alloc(4096ull * 1536 * 4);  // (B,T,3H) y@WihY^T+bih
  float* enc_out   = (float*)alloc(4096ull * 512 * 4);   // (B,S,H) fp32 h
  float* enc_proj  = (float*)alloc(4096ull * 512 * 4);   // (B,S,H)
  float* dec_seq   = (float*)alloc(4096ull * 512 * 4);   // (B,T,H) fp32 h
  bf16*  enc_out_b = (bf16*)alloc(4096ull * 512 * 2);
  bf16*  dec_out_b = (bf16*)alloc(4096ull * 512 * 2);
  bf16*  xs_b      = (bf16*)alloc(4096ull * 256 * 2);
  bf16*  ys_b      = (bf16*)alloc(4096ull * 256 * 2);
  bf16*  encWhh_t  = (bf16*)alloc(512ull * 1536 * 2);
  bf16*  Wcat_t    = (bf16*)alloc(512ull * 2048 * 2);
  bf16*  Wihctx_t  = (bf16*)alloc(512ull * 1536 * 2);
  bf16*  encWih_b  = (bf16*)alloc(1536ull * 256 * 2);
  bf16*  decWihY_b = (bf16*)alloc(1536ull * 256 * 2);
  bf16*  attnWe_b  = (bf16*)alloc(512ull * 512 * 2);
  bf16*  fcW_b     = (bf16*)alloc(16000ull * 512 * 2);
  float* gh_ws     = (float*)alloc(32ull * 1536 * 4);
  float* hW_ws     = (float*)alloc(32ull * 512 * 4);
  unsigned* bar_ws = (unsigned*)alloc(4096ull * 4);      // enc @0, dec @2048

  embed_gather<<<1024, 256, 0, stream>>>(src, tgt, emb_src, emb_tgt, xs_b, ys_b);
  transpose_w<<<10240, 256, 0, stream>>>(enc_Whh, dec_Whh, attn_W, dec_Wih,
                                         encWhh_t, Wcat_t, Wihctx_t);
  pack_weights<<<36096, 256, 0, stream>>>(enc_Wih, dec_Wih, attn_W, fc_W,
                                          encWih_b, decWihY_b, attnWe_b, fcW_b,
                                          bar_ws);

  // enc_gi = xs @ enc_Wih^T + bih   (M=4096, N=1536, K=256)
  gemm_bt<<<dim3(12, 32), 256, 0, stream>>>(xs_b, 256, encWih_b, 256,
                                            enc_gi, 1536, enc_bih, 256);
  // dec_gi_y = ys @ dec_Wih[:, :E]^T + bih
  gemm_bt<<<dim3(12, 32), 256, 0, stream>>>(ys_b, 256, decWihY_b, 256,
                                            dec_gi_y, 1536, dec_bih, 256);

  // encoder recurrence: persistent cooperative kernel, two-level barrier
  {
    unsigned* barf = bar_ws;
    void* args[] = {(void*)&enc_gi, (void*)&encWhh_t, (void*)&enc_bhh,
                    (void*)&enc_out, (void*)&enc_out_b, (void*)&barf};
    hipLaunchCooperativeKernel((void*)enc_loop, dim3(256), dim3(512),
                               args, 0, stream);
  }

  // enc_proj = enc_out @ We^T + attn_b  (M=4096, N=512, K=512)
  gemm_bt<<<dim3(4, 32), 256, 0, stream>>>(enc_out_b, 512, attnWe_b, 512,
                                           enc_proj, 512, attn_b, 512);

  // decoder recurrence: persistent cooperative kernel, two-level barrier
  {
    unsigned* barf = bar_ws + 2048;
    void* args[] = {(void*)&enc_out, (void*)&enc_proj, (void*)&Wcat_t,
                    (void*)&Wihctx_t, (void*)&dec_gi_y, (void*)&dec_bhh,
                    (void*)&attn_v, (void*)&dec_seq, (void*)&dec_out_b,
                    (void*)&gh_ws, (void*)&hW_ws, (void*)&barf};
    hipLaunchCooperativeKernel((void*)dec_loop, dim3(256), dim3(512),
                               args, 0, stream);
  }

  // logits = dec_out @ fc_W^T + fc_b  (M=4096, N=16000, K=512) -> fp32 out
  gemm_bt<<<dim3(125, 32), 256, 0, stream>>>(dec_out_b, 512, fcW_b, 512,
                                             out, VTsz, fc_b, 512);
}

// Round 6
// 6469.341 us; speedup vs baseline: 3.3278x; 1.0436x over previous
//
#include <hip/hip_runtime.h>
#include <hip/hip_bf16.h>

using bf16 = __hip_bfloat16;
typedef short bf16x8_t __attribute__((ext_vector_type(8)));   // 8 bf16 (4 VGPRs)
typedef float f32x4_t __attribute__((ext_vector_type(4)));

// sizes
#define Bsz 32
#define Ssz 128
#define Tsz 128
#define Esz 256
#define Hsz 512
#define VTsz 16000

#define SCOPE_AGENT __HIP_MEMORY_SCOPE_AGENT

__device__ inline float sigm(float x)      { return 1.f / (1.f + __expf(-x)); }
__device__ inline float tanh_fast(float x) { return 1.f - 2.f / (1.f + __expf(2.f * x)); }

// ---- coherent (device-scope, LLC-resident) scalar exchange helpers --------
__device__ inline float cload(const float* p) {
  return __hip_atomic_load(p, __ATOMIC_RELAXED, SCOPE_AGENT);
}
__device__ inline void cstore(float* p, float v) {
  __hip_atomic_store(p, v, __ATOMIC_RELAXED, SCOPE_AGENT);
}

// ---- two-level flag barrier for 256 blocks --------------------------------
// Region layout (word offsets in R, region = 1280 words):
//   [0..255]       per-block arrival flags (block bid stores epoch)
//   [256 + g*64]   group flags, g in 0..15 (256B apart -> distinct lines)
// Flow: block stores R[bid]; 16 leaders (bid%16==0) each poll their group's
// 16 arrival flags (ONE 64B line, single reader) and store the group flag;
// every block's wave 0 then polls the 16 spread group-flag lines.
// Visibility: __syncthreads() drains each wave's vmcnt(0), so a block's sc1
// data stores are at the LLC before its arrival-flag store issues; the
// leader/group-flag observation chain preserves that transitively.
// Epochs are monotonic; no reset between uses (pack_weights zeroes once
// per replay, before the persistent kernels run).
__device__ inline void gbar(unsigned* R, unsigned epoch) {
  __syncthreads();
  const int bid = blockIdx.x, tid = threadIdx.x;
  if (tid == 0)
    __hip_atomic_store(&R[bid], epoch, __ATOMIC_RELAXED, SCOPE_AGENT);
  if ((bid & 15) == 0 && tid < 64) {          // group leader, wave 0
    const int g = bid >> 4;
    for (;;) {
      bool ok = true;
      if (tid < 16)
        ok = __hip_atomic_load(&R[g * 16 + tid], __ATOMIC_RELAXED, SCOPE_AGENT) >= epoch;
      if (__all(ok)) break;
      __builtin_amdgcn_s_sleep(1);
    }
    if (tid == 0)
      __hip_atomic_store(&R[256 + g * 64], epoch, __ATOMIC_RELAXED, SCOPE_AGENT);
  }
  if (tid < 64) {                             // all blocks: poll group flags
    for (;;) {
      bool ok = true;
      if (tid < 16)
        ok = __hip_atomic_load(&R[256 + tid * 64], __ATOMIC_RELAXED, SCOPE_AGENT) >= epoch;
      if (__all(ok)) break;
      __builtin_amdgcn_s_sleep(1);
    }
  }
  __syncthreads();
}

__device__ inline unsigned pack2(float x, float y) {
  unsigned short lo = __builtin_bit_cast(unsigned short, __float2bfloat16(x));
  unsigned short hi = __builtin_bit_cast(unsigned short, __float2bfloat16(y));
  return (unsigned)lo | ((unsigned)hi << 16);
}

__device__ inline uint4 f32x8_to_bf16x8(const float* s) {
  float4 a = *(const float4*)s;
  float4 b = *(const float4*)(s + 4);
  uint4 r;
  r.x = pack2(a.x, a.y); r.y = pack2(a.z, a.w);
  r.z = pack2(b.x, b.y); r.w = pack2(b.z, b.w);
  return r;
}

// ---------------------------------------------------------------------------
// Embedding gather + f32->bf16.
// ---------------------------------------------------------------------------
__global__ __launch_bounds__(256) void embed_gather(
    const int* __restrict__ src, const int* __restrict__ tgt,
    const float* __restrict__ es, const float* __restrict__ et,
    bf16* __restrict__ xs_b, bf16* __restrict__ ys_b)
{
  int idx = blockIdx.x * 256 + threadIdx.x;     // 0 .. 262143
  int which = idx >> 17;                        // 131072 chunks per tensor
  int c = idx & 131071;
  int row = c >> 5;                             // 32 chunks per row (E=256)
  int cc = c & 31;
  if (which == 0) {
    int tok = src[row];
    *(uint4*)(xs_b + (size_t)row * Esz + cc * 8) =
        f32x8_to_bf16x8(es + (size_t)tok * Esz + cc * 8);
  } else {
    int tok = tgt[row];
    *(uint4*)(ys_b + (size_t)row * Esz + cc * 8) =
        f32x8_to_bf16x8(et + (size_t)tok * Esz + cc * 8);
  }
}

// ---------------------------------------------------------------------------
// Weight transposes (f32 src -> bf16 dst, k-major for recurrent kernels).
// ---------------------------------------------------------------------------
__global__ __launch_bounds__(256) void transpose_w(
    const float* __restrict__ enc_Whh, const float* __restrict__ dec_Whh,
    const float* __restrict__ attn_W,  const float* __restrict__ dec_Wih,
    bf16* __restrict__ encWhh_t, bf16* __restrict__ Wcat_t, bf16* __restrict__ Wihctx_t)
{
  int idx = blockIdx.x * 256 + threadIdx.x;
  const int N1 = 512 * 1536, N2 = 512 * 2048;
  if (idx < N1) {
    int k = idx / 1536, j = idx % 1536;
    encWhh_t[idx] = __float2bfloat16(enc_Whh[(size_t)j * 512 + k]);
  } else if (idx < N1 + N2) {
    int r = idx - N1;
    int k = r / 2048, j = r % 2048;
    float v = (j < 1536) ? dec_Whh[(size_t)j * 512 + k]
                         : attn_W[(size_t)(j - 1536) * 1024 + k];
    Wcat_t[r] = __float2bfloat16(v);
  } else {
    int r = idx - N1 - N2;
    int k = r / 1536, j = r % 1536;
    Wihctx_t[r] = __float2bfloat16(dec_Wih[(size_t)j * 768 + 256 + k]);
  }
}

// ---------------------------------------------------------------------------
// Pack GEMM B-operands f32 -> bf16 (row-major, packed). Also zeroes the
// grid-barrier state (runs before the persistent loops on every replay).
// ---------------------------------------------------------------------------
__global__ __launch_bounds__(256) void pack_weights(
    const float* __restrict__ enc_Wih, const float* __restrict__ dec_Wih,
    const float* __restrict__ attn_W,  const float* __restrict__ fc_W,
    bf16* __restrict__ encWih_b, bf16* __restrict__ decWihY_b,
    bf16* __restrict__ attnWe_b, bf16* __restrict__ fcW_b,
    unsigned* __restrict__ bar_ws)
{
  int idx = blockIdx.x * 256 + threadIdx.x;
  if (idx < 4096) bar_ws[idx] = 0u;   // enc region [0..1279], dec [2048..3327]
  const int R1 = 1536 * 256, R2 = 1536 * 256, R3 = 512 * 512;
  if (idx < R1) {
    encWih_b[idx] = __float2bfloat16(enc_Wih[idx]);
  } else if (idx < R1 + R2) {
    int r = idx - R1;
    int row = r >> 8, col = r & 255;
    decWihY_b[r] = __float2bfloat16(dec_Wih[(size_t)row * 768 + col]);
  } else if (idx < R1 + R2 + R3) {
    int r = idx - R1 - R2;
    int row = r >> 9, col = r & 511;
    attnWe_b[r] = __float2bfloat16(attn_W[(size_t)row * 1024 + 512 + col]);
  } else {
    int r = idx - R1 - R2 - R3;
    fcW_b[r] = __float2bfloat16(fc_W[r]);
  }
}

// ---------------------------------------------------------------------------
// MFMA GEMM: C[m,n] = sum_k A[m,k]*B[n,k] + bias[n]. 128x128 tile, BK=64.
// ---------------------------------------------------------------------------
__global__ __launch_bounds__(256) void gemm_bt(
    const bf16* __restrict__ A, int lda,
    const bf16* __restrict__ B, int ldb,
    float* __restrict__ C, int ldc,
    const float* __restrict__ bias, int K)
{
  __shared__ __align__(16) bf16 As[128 * 64];
  __shared__ __align__(16) bf16 Bs[128 * 64];
  const int tid = threadIdx.x;
  const int m0 = blockIdx.y * 128, n0 = blockIdx.x * 128;
  const int lane = tid & 63, wave = tid >> 6;
  const int wm = (wave >> 1) * 64, wn = (wave & 1) * 64;
  const int fr = lane & 15, quad = lane >> 4;

  f32x4_t acc[4][4];
  const f32x4_t zero = {0.f, 0.f, 0.f, 0.f};
#pragma unroll
  for (int i = 0; i < 4; ++i)
#pragma unroll
    for (int j = 0; j < 4; ++j) acc[i][j] = zero;

  for (int k0 = 0; k0 < K; k0 += 64) {
    __syncthreads();
#pragma unroll
    for (int j = 0; j < 4; ++j) {
      int c = j * 256 + tid;
      int row = c >> 3, cc = c & 7;    // 8 chunks of 16B per 64-col row
      *(uint4*)(As + row * 64 + cc * 8) =
          *(const uint4*)(A + (size_t)(m0 + row) * lda + k0 + cc * 8);
      *(uint4*)(Bs + row * 64 + cc * 8) =
          *(const uint4*)(B + (size_t)(n0 + row) * ldb + k0 + cc * 8);
    }
    __syncthreads();
#pragma unroll
    for (int kk = 0; kk < 64; kk += 32) {
      bf16x8_t af[4], bfr[4];
#pragma unroll
      for (int mt = 0; mt < 4; ++mt)
        af[mt] = *(const bf16x8_t*)(As + (wm + mt * 16 + fr) * 64 + kk + quad * 8);
#pragma unroll
      for (int nt = 0; nt < 4; ++nt)
        bfr[nt] = *(const bf16x8_t*)(Bs + (wn + nt * 16 + fr) * 64 + kk + quad * 8);
#pragma unroll
      for (int mt = 0; mt < 4; ++mt)
#pragma unroll
        for (int nt = 0; nt < 4; ++nt)
          acc[mt][nt] = __builtin_amdgcn_mfma_f32_16x16x32_bf16(
              af[mt], bfr[nt], acc[mt][nt], 0, 0, 0);
    }
  }

#pragma unroll
  for (int mt = 0; mt < 4; ++mt) {
#pragma unroll
    for (int nt = 0; nt < 4; ++nt) {
      int n = n0 + wn + nt * 16 + fr;
      float bv = bias[n];
#pragma unroll
      for (int r = 0; r < 4; ++r) {
        int m = m0 + wm + mt * 16 + quad * 4 + r;
        C[(size_t)m * ldc + n] = acc[mt][nt][r] + bv;
      }
    }
  }
}

// ---------------------------------------------------------------------------
// Persistent ENCODER loop. grid = 256 blocks (32 b x 8 i-tiles), 512 thr
// (64 i-lanes x 8 k-groups). One barrier per timestep.
// ---------------------------------------------------------------------------
__global__ __launch_bounds__(512) void enc_loop(
    const float* __restrict__ enc_gi, const bf16* __restrict__ Wt,
    const float* __restrict__ bhh, float* __restrict__ enc_out,
    bf16* __restrict__ enc_out_b, unsigned* __restrict__ barf)
{
  __shared__ float hs[Hsz];
  __shared__ float ps[8][3][64];
  const int b = blockIdx.x >> 3, it = blockIdx.x & 7;
  const int tid = threadIdx.x, il = tid & 63, kg = tid >> 6;   // kg 0..7
  const int i = it * 64 + il;

  for (int k = tid; k < Hsz; k += 512) hs[k] = 0.f;
  __syncthreads();

  unsigned epoch = 0;
  for (int t = 0; t < Ssz; ++t) {
    float pr = 0.f, pz = 0.f, pn = 0.f;
#pragma unroll 8
    for (int k = kg * 64; k < kg * 64 + 64; ++k) {
      const float hv = hs[k];
      const bf16* w = Wt + (size_t)k * 1536;
      pr += hv * (float)w[i];
      pz += hv * (float)w[Hsz + i];
      pn += hv * (float)w[2 * Hsz + i];
    }
    ps[kg][0][il] = pr; ps[kg][1][il] = pz; ps[kg][2][il] = pn;
    __syncthreads();

    if (tid < 64) {
      float ghr = 0.f, ghz = 0.f, ghn = 0.f;
#pragma unroll
      for (int g = 0; g < 8; ++g) {
        ghr += ps[g][0][il]; ghz += ps[g][1][il]; ghn += ps[g][2][il];
      }
      ghr += bhh[i]; ghz += bhh[Hsz + i]; ghn += bhh[2 * Hsz + i];
      const float* gi = enc_gi + ((size_t)b * Ssz + t) * 1536;
      const float r = sigm(gi[i] + ghr);
      const float z = sigm(gi[Hsz + i] + ghz);
      const float n = tanh_fast(gi[2 * Hsz + i] + r * ghn);
      const float h2 = (1.f - z) * n + z * hs[i];
      const size_t o = ((size_t)b * Ssz + t) * Hsz + i;
      cstore(&enc_out[o], h2);
      enc_out_b[o] = __float2bfloat16(h2);
    }

    if (t + 1 < Ssz) {                 // last step: kernel end provides visibility
      gbar(barf, ++epoch);
      const float* hsrc = enc_out + ((size_t)b * Ssz + t) * Hsz;
      for (int k = tid; k < Hsz; k += 512) hs[k] = cload(hsrc + k);
      __syncthreads();
    }
  }
}

// ---------------------------------------------------------------------------
// Persistent DECODER loop. grid = 256 blocks x 512 thr. TWO phases per step:
//   P1  (all blocks): gh = h@Whh^T + bhh ; hW = h@Wh^T  (k-split x2)
//   --- barrier ---
//   P23 (all blocks): scores -> softmax -> ctx (kept in LDS; each of the 8
//        blocks of a batch computes identical values -> bit-identical), then
//        gi_ctx = ctx@Wihctx^T ; gates ; h(t).  NO barrier between P2 and P3.
//   --- barrier (h(t) visible for next P1) ---
// XCD-affinity mapping: consecutive blockIdx round-robin across the 8 XCDs
// (bid&7 = XCD, perf heuristic only). Pin all 8 tiles of a batch to ONE XCD
// (4 batches/XCD) so the per-batch enc_out/enc_proj set (512 KB) and shared
// weights stay resident in that XCD's 4 MB L2 across steps -- P2's 8x
// redundant streams become L2 hits (round-5 FETCH_SIZE was 8.7 GB/dispatch
// at 1.6 TB/s = the whole dispatch time). Bijection on (batch, tile), so
// numerics are unchanged.
// Cross-block data (gh_ws, hW_ws, dec_seq) via cload/cstore only.
// ---------------------------------------------------------------------------
__global__ __launch_bounds__(512) void dec_loop(
    const float* __restrict__ enc_out, const float* __restrict__ enc_proj,
    const bf16* __restrict__ Wcat_t, const bf16* __restrict__ Wihctx_t,
    const float* __restrict__ dec_gi_y, const float* __restrict__ dbhh,
    const float* __restrict__ attn_v, float* __restrict__ dec_seq,
    bf16* __restrict__ dec_out_b, float* __restrict__ gh_ws,
    float* __restrict__ hW_ws, unsigned* __restrict__ barf)
{
  const int bid = blockIdx.x, tid = threadIdx.x;
  const int xcd = bid & 7, grp = bid >> 3;
  const int b1 = xcd * 4 + (grp >> 3);     // 4 batches per XCD
  const int tile = grp & 7;                // 8 tiles (blocks) per batch
  // P1 mapping: j = tile*256 + (tid&255), k-half = tid>>8
  const int jl = tid & 255, kh = tid >> 8;
  const int j = tile * 256 + jl;
  // P3 mapping: i3 = tile*64 + (tid&63), k-group = tid>>6
  const int il = tid & 63, kg = tid >> 6;
  const int i3 = tile * 64 + il;

  __shared__ float hs[Hsz];                     // P1 h state
  __shared__ float ps1[2][256];                 // P1 partials
  __shared__ float hw[Hsz], vv[Hsz], sc[Ssz];   // P2
  __shared__ float red[2], red2[2];             // P2
  __shared__ float cs[Hsz];                     // ctx (stays in LDS)
  __shared__ float ps[8][3][64];                // P3 partials

  for (int k = tid; k < Hsz; k += 512) vv[k] = attn_v[k];
  __syncthreads();

  unsigned epoch = 0;
  for (int t = 0; t < Tsz; ++t) {
    // ---------------- phase 1 ----------------
    {
      const float* hsrc = (t == 0)
          ? (enc_out + ((size_t)b1 * Ssz + (Ssz - 1)) * Hsz)
          : (dec_seq + ((size_t)b1 * Tsz + (t - 1)) * Hsz);
      for (int k = tid; k < Hsz; k += 512) hs[k] = cload(hsrc + k);
      __syncthreads();
      float p = 0.f;
#pragma unroll 16
      for (int k = kh * 256; k < kh * 256 + 256; ++k)
        p += hs[k] * (float)Wcat_t[(size_t)k * 2048 + j];
      ps1[kh][jl] = p;
      __syncthreads();
      if (tid < 256) {
        float s = ps1[0][jl] + ps1[1][jl];
        if (j < 1536) cstore(&gh_ws[b1 * 1536 + j], s + dbhh[j]);
        else          cstore(&hW_ws[b1 * Hsz + (j - 1536)], s);
      }
    }
    gbar(barf, ++epoch);

    // ---------------- phase 2 (redundant per 8 blocks, ctx -> LDS) --------
    {
      for (int k = tid; k < Hsz; k += 512) hw[k] = cload(&hW_ws[b1 * Hsz + k]);
      __syncthreads();
      const int wv = tid >> 6;                  // 8 waves, 16 s each
      for (int s = wv; s < Ssz; s += 8) {
        const float* epj = enc_proj + ((size_t)b1 * Ssz + s) * Hsz;
        float pp = 0.f;
#pragma unroll
        for (int q = 0; q < 8; ++q) {
          int k = q * 64 + il;
          pp += tanh_fast(hw[k] + epj[k]) * vv[k];
        }
#pragma unroll
        for (int off = 32; off; off >>= 1) pp += __shfl_down(pp, off);
        if (il == 0) sc[s] = pp;
      }
      __syncthreads();
      if (tid < 128) {
        float v = sc[tid];
#pragma unroll
        for (int off = 32; off; off >>= 1) v = fmaxf(v, __shfl_down(v, off));
        if (il == 0) red[tid >> 6] = v;
      }
      __syncthreads();
      const float mx = fmaxf(red[0], red[1]);
      if (tid < 128) {
        float e = __expf(sc[tid] - mx);
        sc[tid] = e;
        float v = e;
#pragma unroll
        for (int off = 32; off; off >>= 1) v += __shfl_down(v, off);
        if (il == 0) red2[tid >> 6] = v;
      }
      __syncthreads();
      const float inv = 1.f / (red2[0] + red2[1]);
      for (int k = tid; k < Hsz; k += 512) {
        float a = 0.f;
#pragma unroll 8
        for (int s = 0; s < Ssz; ++s)
          a += sc[s] * enc_out[((size_t)b1 * Ssz + s) * Hsz + k];
        cs[k] = a * inv;
      }
      __syncthreads();
    }

    // ---------------- phase 3 (same block, no barrier needed) -------------
    {
      float pr = 0.f, pz = 0.f, pn = 0.f;
#pragma unroll 8
      for (int k = kg * 64; k < kg * 64 + 64; ++k) {
        const float c = cs[k];
        const bf16* w = Wihctx_t + (size_t)k * 1536;
        pr += c * (float)w[i3];
        pz += c * (float)w[Hsz + i3];
        pn += c * (float)w[2 * Hsz + i3];
      }
      ps[kg][0][il] = pr; ps[kg][1][il] = pz; ps[kg][2][il] = pn;
      __syncthreads();
      if (tid < 64) {
        float sr = 0.f, sz = 0.f, sn = 0.f;
#pragma unroll
        for (int g = 0; g < 8; ++g) {
          sr += ps[g][0][il]; sz += ps[g][1][il]; sn += ps[g][2][il];
        }
        const float* giy = dec_gi_y + ((size_t)b1 * Tsz + t) * 1536;
        float gir = giy[i3] + sr;
        float giz = giy[Hsz + i3] + sz;
        float gin = giy[2 * Hsz + i3] + sn;
        float ghr = cload(&gh_ws[b1 * 1536 + i3]);
        float ghz = cload(&gh_ws[b1 * 1536 + Hsz + i3]);
        float ghn = cload(&gh_ws[b1 * 1536 + 2 * Hsz + i3]);
        const float* hsrc = (t == 0)
            ? (enc_out + ((size_t)b1 * Ssz + (Ssz - 1)) * Hsz)
            : (dec_seq + ((size_t)b1 * Tsz + (t - 1)) * Hsz);
        float hp = cload(hsrc + i3);
        const float r = sigm(gir + ghr);
        const float z = sigm(giz + ghz);
        const float n = tanh_fast(gin + r * ghn);
        const float h2 = (1.f - z) * n + z * hp;
        const size_t o = ((size_t)b1 * Tsz + t) * Hsz + i3;
        cstore(&dec_seq[o], h2);
        dec_out_b[o] = __float2bfloat16(h2);
      }
    }
    if (t + 1 < Tsz) gbar(barf, ++epoch);  // last step: kernel end flushes
  }
}

// ---------------------------------------------------------------------------
extern "C" void kernel_launch(void* const* d_in, const int* in_sizes, int n_in,
                              void* d_out, int out_size, void* d_ws, size_t ws_size,
                              hipStream_t stream) {
  const int*   src      = (const int*)d_in[0];
  const int*   tgt      = (const int*)d_in[1];
  const float* emb_src  = (const float*)d_in[2];
  const float* emb_tgt  = (const float*)d_in[3];
  const float* enc_Wih  = (const float*)d_in[4];
  const float* enc_Whh  = (const float*)d_in[5];
  const float* enc_bih  = (const float*)d_in[6];
  const float* enc_bhh  = (const float*)d_in[7];
  const float* dec_Wih  = (const float*)d_in[8];
  const float* dec_Whh  = (const float*)d_in[9];
  const float* dec_bih  = (const float*)d_in[10];
  const float* dec_bhh  = (const float*)d_in[11];
  const float* attn_W   = (const float*)d_in[12];
  const float* attn_b   = (const float*)d_in[13];
  const float* attn_v   = (const float*)d_in[14];
  const float* fc_W     = (const float*)d_in[15];
  const float* fc_b     = (const float*)d_in[16];
  float* out = (float*)d_out;

  char* p = (char*)d_ws;
  auto alloc = [&](size_t n) { char* r = p; p += (n + 255) & ~(size_t)255; return r; };
  float* enc_gi    = (float*)alloc(4096ull * 1536 * 4);  // (B,S,3H) x@Wih^T+bih
  float* dec_gi_y  = (float*)alloc(4096ull * 1536 * 4);  // (B,T,3H) y@WihY^T+bih
  float* enc_out   = (float*)alloc(4096ull * 512 * 4);   // (B,S,H) fp32 h
  float* enc_proj  = (float*)alloc(4096ull * 512 * 4);   // (B,S,H)
  float* dec_seq   = (float*)alloc(4096ull * 512 * 4);   // (B,T,H) fp32 h
  bf16*  enc_out_b = (bf16*)alloc(4096ull * 512 * 2);
  bf16*  dec_out_b = (bf16*)alloc(4096ull * 512 * 2);
  bf16*  xs_b      = (bf16*)alloc(4096ull * 256 * 2);
  bf16*  ys_b      = (bf16*)alloc(4096ull * 256 * 2);
  bf16*  encWhh_t  = (bf16*)alloc(512ull * 1536 * 2);
  bf16*  Wcat_t    = (bf16*)alloc(512ull * 2048 * 2);
  bf16*  Wihctx_t  = (bf16*)alloc(512ull * 1536 * 2);
  bf16*  encWih_b  = (bf16*)alloc(1536ull * 256 * 2);
  bf16*  decWihY_b = (bf16*)alloc(1536ull * 256 * 2);
  bf16*  attnWe_b  = (bf16*)alloc(512ull * 512 * 2);
  bf16*  fcW_b     = (bf16*)alloc(16000ull * 512 * 2);
  float* gh_ws     = (float*)alloc(32ull * 1536 * 4);
  float* hW_ws     = (float*)alloc(32ull * 512 * 4);
  unsigned* bar_ws = (unsigned*)alloc(4096ull * 4);      // enc @0, dec @2048

  embed_gather<<<1024, 256, 0, stream>>>(src, tgt, emb_src, emb_tgt, xs_b, ys_b);
  transpose_w<<<10240, 256, 0, stream>>>(enc_Whh, dec_Whh, attn_W, dec_Wih,
                                         encWhh_t, Wcat_t, Wihctx_t);
  pack_weights<<<36096, 256, 0, stream>>>(enc_Wih, dec_Wih, attn_W, fc_W,
                                          encWih_b, decWihY_b, attnWe_b, fcW_b,
                                          bar_ws);

  // enc_gi = xs @ enc_Wih^T + bih   (M=4096, N=1536, K=256)
  gemm_bt<<<dim3(12, 32), 256, 0, stream>>>(xs_b, 256, encWih_b, 256,
                                            enc_gi, 1536, enc_bih, 256);
  // dec_gi_y = ys @ dec_Wih[:, :E]^T + bih
  gemm_bt<<<dim3(12, 32), 256, 0, stream>>>(ys_b, 256, decWihY_b, 256,
                                            dec_gi_y, 1536, dec_bih, 256);

  // encoder recurrence: persistent cooperative kernel, two-level barrier
  {
    unsigned* barf = bar_ws;
    void* args[] = {(void*)&enc_gi, (void*)&encWhh_t, (void*)&enc_bhh,
                    (void*)&enc_out, (void*)&enc_out_b, (void*)&barf};
    hipLaunchCooperativeKernel((void*)enc_loop, dim3(256), dim3(512),
                               args, 0, stream);
  }

  // enc_proj = enc_out @ We^T + attn_b  (M=4096, N=512, K=512)
  gemm_bt<<<dim3(4, 32), 256, 0, stream>>>(enc_out_b, 512, attnWe_b, 512,
                                           enc_proj, 512, attn_b, 512);

  // decoder recurrence: persistent cooperative kernel, two-level barrier
  {
    unsigned* barf = bar_ws + 2048;
    void* args[] = {(void*)&enc_out, (void*)&enc_proj, (void*)&Wcat_t,
                    (void*)&Wihctx_t, (void*)&dec_gi_y, (void*)&dec_bhh,
                    (void*)&attn_v, (void*)&dec_seq, (void*)&dec_out_b,
                    (void*)&gh_ws, (void*)&hW_ws, (void*)&barf};
    hipLaunchCooperativeKernel((void*)dec_loop, dim3(256), dim3(512),
                               args, 0, stream);
  }

  // logits = dec_out @ fc_W^T + fc_b  (M=4096, N=16000, K=512) -> fp32 out
  gemm_bt<<<dim3(125, 32), 256, 0, stream>>>(dec_out_b, 512, fcW_b, 512,
                                             out, VTsz, fc_b, 512);
}

// Round 7
// 6227.551 us; speedup vs baseline: 3.4570x; 1.0388x over previous
//
#include <hip/hip_runtime.h>
#include <hip/hip_bf16.h>

using bf16 = __hip_bfloat16;
typedef short bf16x8_t __attribute__((ext_vector_type(8)));   // 8 bf16 (4 VGPRs)
typedef float f32x4_t __attribute__((ext_vector_type(4)));

// sizes
#define Bsz 32
#define Ssz 128
#define Tsz 128
#define Esz 256
#define Hsz 512
#define VTsz 16000

#define SCOPE_AGENT __HIP_MEMORY_SCOPE_AGENT

__device__ inline float sigm(float x)      { return 1.f / (1.f + __expf(-x)); }
__device__ inline float tanh_fast(float x) { return 1.f - 2.f / (1.f + __expf(2.f * x)); }

// ---- coherent (device-scope, LLC-resident) scalar exchange helpers --------
__device__ inline float cload(const float* p) {
  return __hip_atomic_load(p, __ATOMIC_RELAXED, SCOPE_AGENT);
}
__device__ inline void cstore(float* p, float v) {
  __hip_atomic_store(p, v, __ATOMIC_RELAXED, SCOPE_AGENT);
}

// ---- PER-BATCH 8-block barrier --------------------------------------------
// After the round-5 P2+P3 merge, every per-step dependency is contained in
// one batch's 8 blocks (P1 reads own batch h(t-1); P2/P3 read own batch
// gh/hW). So sync only within the batch: batch b owns ONE 64B line of 8
// epoch flags (R[b*16 .. b*16+7]). Block (b,tile) stores its epoch; lanes
// 0..7 of wave 0 poll the line until __all(flag >= epoch). ~2 LLC round
// trips (~0.3-0.5us) and NO cross-batch skew coupling -- 32 independent
// pipelines instead of one grid-wide straggler chain (round-6 lesson:
// global barrier skew was ~30us/step of the 41.6us).
// Visibility: __syncthreads() drains each wave's vmcnt(0), so the block's
// sc1 data stores are at the LLC before its flag store issues; peers poll
// the flag then cload the data (sc1, coherent at LLC). Epochs monotonic;
// pack_weights zeroes the region each replay before the persistent loops.
__device__ inline void pbar(unsigned* R, int b, int tile, unsigned epoch) {
  __syncthreads();
  const int tid = threadIdx.x;
  if (tid == 0)
    __hip_atomic_store(&R[b * 16 + tile], epoch, __ATOMIC_RELAXED, SCOPE_AGENT);
  if (tid < 64) {
    for (;;) {
      bool ok = true;
      if (tid < 8)
        ok = __hip_atomic_load(&R[b * 16 + tid], __ATOMIC_RELAXED, SCOPE_AGENT) >= epoch;
      if (__all(ok)) break;
      __builtin_amdgcn_s_sleep(1);
    }
  }
  __syncthreads();
}

__device__ inline unsigned pack2(float x, float y) {
  unsigned short lo = __builtin_bit_cast(unsigned short, __float2bfloat16(x));
  unsigned short hi = __builtin_bit_cast(unsigned short, __float2bfloat16(y));
  return (unsigned)lo | ((unsigned)hi << 16);
}

__device__ inline uint4 f32x8_to_bf16x8(const float* s) {
  float4 a = *(const float4*)s;
  float4 b = *(const float4*)(s + 4);
  uint4 r;
  r.x = pack2(a.x, a.y); r.y = pack2(a.z, a.w);
  r.z = pack2(b.x, b.y); r.w = pack2(b.z, b.w);
  return r;
}

// ---------------------------------------------------------------------------
// Embedding gather + f32->bf16.
// ---------------------------------------------------------------------------
__global__ __launch_bounds__(256) void embed_gather(
    const int* __restrict__ src, const int* __restrict__ tgt,
    const float* __restrict__ es, const float* __restrict__ et,
    bf16* __restrict__ xs_b, bf16* __restrict__ ys_b)
{
  int idx = blockIdx.x * 256 + threadIdx.x;     // 0 .. 262143
  int which = idx >> 17;                        // 131072 chunks per tensor
  int c = idx & 131071;
  int row = c >> 5;                             // 32 chunks per row (E=256)
  int cc = c & 31;
  if (which == 0) {
    int tok = src[row];
    *(uint4*)(xs_b + (size_t)row * Esz + cc * 8) =
        f32x8_to_bf16x8(es + (size_t)tok * Esz + cc * 8);
  } else {
    int tok = tgt[row];
    *(uint4*)(ys_b + (size_t)row * Esz + cc * 8) =
        f32x8_to_bf16x8(et + (size_t)tok * Esz + cc * 8);
  }
}

// ---------------------------------------------------------------------------
// Weight transposes (f32 src -> bf16 dst, k-major for recurrent kernels).
// ---------------------------------------------------------------------------
__global__ __launch_bounds__(256) void transpose_w(
    const float* __restrict__ enc_Whh, const float* __restrict__ dec_Whh,
    const float* __restrict__ attn_W,  const float* __restrict__ dec_Wih,
    bf16* __restrict__ encWhh_t, bf16* __restrict__ Wcat_t, bf16* __restrict__ Wihctx_t)
{
  int idx = blockIdx.x * 256 + threadIdx.x;
  const int N1 = 512 * 1536, N2 = 512 * 2048;
  if (idx < N1) {
    int k = idx / 1536, j = idx % 1536;
    encWhh_t[idx] = __float2bfloat16(enc_Whh[(size_t)j * 512 + k]);
  } else if (idx < N1 + N2) {
    int r = idx - N1;
    int k = r / 2048, j = r % 2048;
    float v = (j < 1536) ? dec_Whh[(size_t)j * 512 + k]
                         : attn_W[(size_t)(j - 1536) * 1024 + k];
    Wcat_t[r] = __float2bfloat16(v);
  } else {
    int r = idx - N1 - N2;
    int k = r / 1536, j = r % 1536;
    Wihctx_t[r] = __float2bfloat16(dec_Wih[(size_t)j * 768 + 256 + k]);
  }
}

// ---------------------------------------------------------------------------
// Pack GEMM B-operands f32 -> bf16 (row-major, packed). Also zeroes the
// barrier state (runs before the persistent loops on every replay).
// ---------------------------------------------------------------------------
__global__ __launch_bounds__(256) void pack_weights(
    const float* __restrict__ enc_Wih, const float* __restrict__ dec_Wih,
    const float* __restrict__ attn_W,  const float* __restrict__ fc_W,
    bf16* __restrict__ encWih_b, bf16* __restrict__ decWihY_b,
    bf16* __restrict__ attnWe_b, bf16* __restrict__ fcW_b,
    unsigned* __restrict__ bar_ws)
{
  int idx = blockIdx.x * 256 + threadIdx.x;
  if (idx < 4096) bar_ws[idx] = 0u;   // enc region @0 (512 words), dec @2048
  const int R1 = 1536 * 256, R2 = 1536 * 256, R3 = 512 * 512;
  if (idx < R1) {
    encWih_b[idx] = __float2bfloat16(enc_Wih[idx]);
  } else if (idx < R1 + R2) {
    int r = idx - R1;
    int row = r >> 8, col = r & 255;
    decWihY_b[r] = __float2bfloat16(dec_Wih[(size_t)row * 768 + col]);
  } else if (idx < R1 + R2 + R3) {
    int r = idx - R1 - R2;
    int row = r >> 9, col = r & 511;
    attnWe_b[r] = __float2bfloat16(attn_W[(size_t)row * 1024 + 512 + col]);
  } else {
    int r = idx - R1 - R2 - R3;
    fcW_b[r] = __float2bfloat16(fc_W[r]);
  }
}

// ---------------------------------------------------------------------------
// MFMA GEMM: C[m,n] = sum_k A[m,k]*B[n,k] + bias[n]. 128x128 tile, BK=64.
// ---------------------------------------------------------------------------
__global__ __launch_bounds__(256) void gemm_bt(
    const bf16* __restrict__ A, int lda,
    const bf16* __restrict__ B, int ldb,
    float* __restrict__ C, int ldc,
    const float* __restrict__ bias, int K)
{
  __shared__ __align__(16) bf16 As[128 * 64];
  __shared__ __align__(16) bf16 Bs[128 * 64];
  const int tid = threadIdx.x;
  const int m0 = blockIdx.y * 128, n0 = blockIdx.x * 128;
  const int lane = tid & 63, wave = tid >> 6;
  const int wm = (wave >> 1) * 64, wn = (wave & 1) * 64;
  const int fr = lane & 15, quad = lane >> 4;

  f32x4_t acc[4][4];
  const f32x4_t zero = {0.f, 0.f, 0.f, 0.f};
#pragma unroll
  for (int i = 0; i < 4; ++i)
#pragma unroll
    for (int j = 0; j < 4; ++j) acc[i][j] = zero;

  for (int k0 = 0; k0 < K; k0 += 64) {
    __syncthreads();
#pragma unroll
    for (int j = 0; j < 4; ++j) {
      int c = j * 256 + tid;
      int row = c >> 3, cc = c & 7;    // 8 chunks of 16B per 64-col row
      *(uint4*)(As + row * 64 + cc * 8) =
          *(const uint4*)(A + (size_t)(m0 + row) * lda + k0 + cc * 8);
      *(uint4*)(Bs + row * 64 + cc * 8) =
          *(const uint4*)(B + (size_t)(n0 + row) * ldb + k0 + cc * 8);
    }
    __syncthreads();
#pragma unroll
    for (int kk = 0; kk < 64; kk += 32) {
      bf16x8_t af[4], bfr[4];
#pragma unroll
      for (int mt = 0; mt < 4; ++mt)
        af[mt] = *(const bf16x8_t*)(As + (wm + mt * 16 + fr) * 64 + kk + quad * 8);
#pragma unroll
      for (int nt = 0; nt < 4; ++nt)
        bfr[nt] = *(const bf16x8_t*)(Bs + (wn + nt * 16 + fr) * 64 + kk + quad * 8);
#pragma unroll
      for (int mt = 0; mt < 4; ++mt)
#pragma unroll
        for (int nt = 0; nt < 4; ++nt)
          acc[mt][nt] = __builtin_amdgcn_mfma_f32_16x16x32_bf16(
              af[mt], bfr[nt], acc[mt][nt], 0, 0, 0);
    }
  }

#pragma unroll
  for (int mt = 0; mt < 4; ++mt) {
#pragma unroll
    for (int nt = 0; nt < 4; ++nt) {
      int n = n0 + wn + nt * 16 + fr;
      float bv = bias[n];
#pragma unroll
      for (int r = 0; r < 4; ++r) {
        int m = m0 + wm + mt * 16 + quad * 4 + r;
        C[(size_t)m * ldc + n] = acc[mt][nt][r] + bv;
      }
    }
  }
}

// ---------------------------------------------------------------------------
// Persistent ENCODER loop. grid = 256 blocks (32 b x 8 i-tiles), 512 thr
// (64 i-lanes x 8 k-groups). One PER-BATCH barrier per timestep (the step
// dependency -- full h(t) of one batch -- is produced by that batch's own
// 8 tile-blocks; no cross-batch dataflow exists).
// ---------------------------------------------------------------------------
__global__ __launch_bounds__(512) void enc_loop(
    const float* __restrict__ enc_gi, const bf16* __restrict__ Wt,
    const float* __restrict__ bhh, float* __restrict__ enc_out,
    bf16* __restrict__ enc_out_b, unsigned* __restrict__ barf)
{
  __shared__ float hs[Hsz];
  __shared__ float ps[8][3][64];
  const int b = blockIdx.x >> 3, it = blockIdx.x & 7;
  const int tid = threadIdx.x, il = tid & 63, kg = tid >> 6;   // kg 0..7
  const int i = it * 64 + il;

  for (int k = tid; k < Hsz; k += 512) hs[k] = 0.f;
  __syncthreads();

  unsigned epoch = 0;
  for (int t = 0; t < Ssz; ++t) {
    float pr = 0.f, pz = 0.f, pn = 0.f;
#pragma unroll 8
    for (int k = kg * 64; k < kg * 64 + 64; ++k) {
      const float hv = hs[k];
      const bf16* w = Wt + (size_t)k * 1536;
      pr += hv * (float)w[i];
      pz += hv * (float)w[Hsz + i];
      pn += hv * (float)w[2 * Hsz + i];
    }
    ps[kg][0][il] = pr; ps[kg][1][il] = pz; ps[kg][2][il] = pn;
    __syncthreads();

    if (tid < 64) {
      float ghr = 0.f, ghz = 0.f, ghn = 0.f;
#pragma unroll
      for (int g = 0; g < 8; ++g) {
        ghr += ps[g][0][il]; ghz += ps[g][1][il]; ghn += ps[g][2][il];
      }
      ghr += bhh[i]; ghz += bhh[Hsz + i]; ghn += bhh[2 * Hsz + i];
      const float* gi = enc_gi + ((size_t)b * Ssz + t) * 1536;
      const float r = sigm(gi[i] + ghr);
      const float z = sigm(gi[Hsz + i] + ghz);
      const float n = tanh_fast(gi[2 * Hsz + i] + r * ghn);
      const float h2 = (1.f - z) * n + z * hs[i];
      const size_t o = ((size_t)b * Ssz + t) * Hsz + i;
      cstore(&enc_out[o], h2);
      enc_out_b[o] = __float2bfloat16(h2);
    }

    if (t + 1 < Ssz) {                 // last step: kernel end provides visibility
      pbar(barf, b, it, ++epoch);      // own batch's h(t) visible at LLC
      const float* hsrc = enc_out + ((size_t)b * Ssz + t) * Hsz;
      for (int k = tid; k < Hsz; k += 512) hs[k] = cload(hsrc + k);
      __syncthreads();
    }
  }
}

// ---------------------------------------------------------------------------
// Persistent DECODER loop. grid = 256 blocks x 512 thr. TWO phases per step:
//   P1  (all blocks): gh = h@Whh^T + bhh ; hW = h@Wh^T  (k-split x2)
//   --- per-batch barrier ---
//   P23 (all blocks): scores -> softmax -> ctx (kept in LDS; each of the 8
//        blocks of a batch computes identical values -> bit-identical), then
//        gi_ctx = ctx@Wihctx^T ; gates ; h(t).  NO barrier between P2 and P3.
//   --- per-batch barrier (h(t) visible for next P1) ---
// XCD-affinity mapping (round 6): all 8 tiles of a batch pinned to ONE XCD
// so the batch's enc_out/enc_proj (512 KB) stays L2-resident and the
// per-batch barrier line bounces within a small reader set.
// All per-step dependencies are intra-batch, so per-batch sync suffices --
// 32 independent pipelines, no grid-wide straggler coupling.
// Cross-block data (gh_ws, hW_ws, dec_seq) via cload/cstore only.
// ---------------------------------------------------------------------------
__global__ __launch_bounds__(512) void dec_loop(
    const float* __restrict__ enc_out, const float* __restrict__ enc_proj,
    const bf16* __restrict__ Wcat_t, const bf16* __restrict__ Wihctx_t,
    const float* __restrict__ dec_gi_y, const float* __restrict__ dbhh,
    const float* __restrict__ attn_v, float* __restrict__ dec_seq,
    bf16* __restrict__ dec_out_b, float* __restrict__ gh_ws,
    float* __restrict__ hW_ws, unsigned* __restrict__ barf)
{
  const int bid = blockIdx.x, tid = threadIdx.x;
  const int xcd = bid & 7, grp = bid >> 3;
  const int b1 = xcd * 4 + (grp >> 3);     // 4 batches per XCD
  const int tile = grp & 7;                // 8 tiles (blocks) per batch
  // P1 mapping: j = tile*256 + (tid&255), k-half = tid>>8
  const int jl = tid & 255, kh = tid >> 8;
  const int j = tile * 256 + jl;
  // P3 mapping: i3 = tile*64 + (tid&63), k-group = tid>>6
  const int il = tid & 63, kg = tid >> 6;
  const int i3 = tile * 64 + il;

  __shared__ float hs[Hsz];                     // P1 h state
  __shared__ float ps1[2][256];                 // P1 partials
  __shared__ float hw[Hsz], vv[Hsz], sc[Ssz];   // P2
  __shared__ float red[2], red2[2];             // P2
  __shared__ float cs[Hsz];                     // ctx (stays in LDS)
  __shared__ float ps[8][3][64];                // P3 partials

  for (int k = tid; k < Hsz; k += 512) vv[k] = attn_v[k];
  __syncthreads();

  unsigned epoch = 0;
  for (int t = 0; t < Tsz; ++t) {
    // ---------------- phase 1 ----------------
    {
      const float* hsrc = (t == 0)
          ? (enc_out + ((size_t)b1 * Ssz + (Ssz - 1)) * Hsz)
          : (dec_seq + ((size_t)b1 * Tsz + (t - 1)) * Hsz);
      for (int k = tid; k < Hsz; k += 512) hs[k] = cload(hsrc + k);
      __syncthreads();
      float p = 0.f;
#pragma unroll 16
      for (int k = kh * 256; k < kh * 256 + 256; ++k)
        p += hs[k] * (float)Wcat_t[(size_t)k * 2048 + j];
      ps1[kh][jl] = p;
      __syncthreads();
      if (tid < 256) {
        float s = ps1[0][jl] + ps1[1][jl];
        if (j < 1536) cstore(&gh_ws[b1 * 1536 + j], s + dbhh[j]);
        else          cstore(&hW_ws[b1 * Hsz + (j - 1536)], s);
      }
    }
    pbar(barf, b1, tile, ++epoch);

    // ---------------- phase 2 (redundant per 8 blocks, ctx -> LDS) --------
    {
      for (int k = tid; k < Hsz; k += 512) hw[k] = cload(&hW_ws[b1 * Hsz + k]);
      __syncthreads();
      const int wv = tid >> 6;                  // 8 waves, 16 s each
      for (int s = wv; s < Ssz; s += 8) {
        const float* epj = enc_proj + ((size_t)b1 * Ssz + s) * Hsz;
        float pp = 0.f;
#pragma unroll
        for (int q = 0; q < 8; ++q) {
          int k = q * 64 + il;
          pp += tanh_fast(hw[k] + epj[k]) * vv[k];
        }
#pragma unroll
        for (int off = 32; off; off >>= 1) pp += __shfl_down(pp, off);
        if (il == 0) sc[s] = pp;
      }
      __syncthreads();
      if (tid < 128) {
        float v = sc[tid];
#pragma unroll
        for (int off = 32; off; off >>= 1) v = fmaxf(v, __shfl_down(v, off));
        if (il == 0) red[tid >> 6] = v;
      }
      __syncthreads();
      const float mx = fmaxf(red[0], red[1]);
      if (tid < 128) {
        float e = __expf(sc[tid] - mx);
        sc[tid] = e;
        float v = e;
#pragma unroll
        for (int off = 32; off; off >>= 1) v += __shfl_down(v, off);
        if (il == 0) red2[tid >> 6] = v;
      }
      __syncthreads();
      const float inv = 1.f / (red2[0] + red2[1]);
      for (int k = tid; k < Hsz; k += 512) {
        float a = 0.f;
#pragma unroll 8
        for (int s = 0; s < Ssz; ++s)
          a += sc[s] * enc_out[((size_t)b1 * Ssz + s) * Hsz + k];
        cs[k] = a * inv;
      }
      __syncthreads();
    }

    // ---------------- phase 3 (same block, no barrier needed) -------------
    {
      float pr = 0.f, pz = 0.f, pn = 0.f;
#pragma unroll 8
      for (int k = kg * 64; k < kg * 64 + 64; ++k) {
        const float c = cs[k];
        const bf16* w = Wihctx_t + (size_t)k * 1536;
        pr += c * (float)w[i3];
        pz += c * (float)w[Hsz + i3];
        pn += c * (float)w[2 * Hsz + i3];
      }
      ps[kg][0][il] = pr; ps[kg][1][il] = pz; ps[kg][2][il] = pn;
      __syncthreads();
      if (tid < 64) {
        float sr = 0.f, sz = 0.f, sn = 0.f;
#pragma unroll
        for (int g = 0; g < 8; ++g) {
          sr += ps[g][0][il]; sz += ps[g][1][il]; sn += ps[g][2][il];
        }
        const float* giy = dec_gi_y + ((size_t)b1 * Tsz + t) * 1536;
        float gir = giy[i3] + sr;
        float giz = giy[Hsz + i3] + sz;
        float gin = giy[2 * Hsz + i3] + sn;
        float ghr = cload(&gh_ws[b1 * 1536 + i3]);
        float ghz = cload(&gh_ws[b1 * 1536 + Hsz + i3]);
        float ghn = cload(&gh_ws[b1 * 1536 + 2 * Hsz + i3]);
        const float* hsrc = (t == 0)
            ? (enc_out + ((size_t)b1 * Ssz + (Ssz - 1)) * Hsz)
            : (dec_seq + ((size_t)b1 * Tsz + (t - 1)) * Hsz);
        float hp = cload(hsrc + i3);
        const float r = sigm(gir + ghr);
        const float z = sigm(giz + ghz);
        const float n = tanh_fast(gin + r * ghn);
        const float h2 = (1.f - z) * n + z * hp;
        const size_t o = ((size_t)b1 * Tsz + t) * Hsz + i3;
        cstore(&dec_seq[o], h2);
        dec_out_b[o] = __float2bfloat16(h2);
      }
    }
    if (t + 1 < Tsz) pbar(barf, b1, tile, ++epoch);  // last step: kernel end flushes
  }
}

// ---------------------------------------------------------------------------
extern "C" void kernel_launch(void* const* d_in, const int* in_sizes, int n_in,
                              void* d_out, int out_size, void* d_ws, size_t ws_size,
                              hipStream_t stream) {
  const int*   src      = (const int*)d_in[0];
  const int*   tgt      = (const int*)d_in[1];
  const float* emb_src  = (const float*)d_in[2];
  const float* emb_tgt  = (const float*)d_in[3];
  const float* enc_Wih  = (const float*)d_in[4];
  const float* enc_Whh  = (const float*)d_in[5];
  const float* enc_bih  = (const float*)d_in[6];
  const float* enc_bhh  = (const float*)d_in[7];
  const float* dec_Wih  = (const float*)d_in[8];
  const float* dec_Whh  = (const float*)d_in[9];
  const float* dec_bih  = (const float*)d_in[10];
  const float* dec_bhh  = (const float*)d_in[11];
  const float* attn_W   = (const float*)d_in[12];
  const float* attn_b   = (const float*)d_in[13];
  const float* attn_v   = (const float*)d_in[14];
  const float* fc_W     = (const float*)d_in[15];
  const float* fc_b     = (const float*)d_in[16];
  float* out = (float*)d_out;

  char* p = (char*)d_ws;
  auto alloc = [&](size_t n) { char* r = p; p += (n + 255) & ~(size_t)255; return r; };
  float* enc_gi    = (float*)alloc(4096ull * 1536 * 4);  // (B,S,3H) x@Wih^T+bih
  float* dec_gi_y  = (float*)alloc(4096ull * 1536 * 4);  // (B,T,3H) y@WihY^T+bih
  float* enc_out   = (float*)alloc(4096ull * 512 * 4);   // (B,S,H) fp32 h
  float* enc_proj  = (float*)alloc(4096ull * 512 * 4);   // (B,S,H)
  float* dec_seq   = (float*)alloc(4096ull * 512 * 4);   // (B,T,H) fp32 h
  bf16*  enc_out_b = (bf16*)alloc(4096ull * 512 * 2);
  bf16*  dec_out_b = (bf16*)alloc(4096ull * 512 * 2);
  bf16*  xs_b      = (bf16*)alloc(4096ull * 256 * 2);
  bf16*  ys_b      = (bf16*)alloc(4096ull * 256 * 2);
  bf16*  encWhh_t  = (bf16*)alloc(512ull * 1536 * 2);
  bf16*  Wcat_t    = (bf16*)alloc(512ull * 2048 * 2);
  bf16*  Wihctx_t  = (bf16*)alloc(512ull * 1536 * 2);
  bf16*  encWih_b  = (bf16*)alloc(1536ull * 256 * 2);
  bf16*  decWihY_b = (bf16*)alloc(1536ull * 256 * 2);
  bf16*  attnWe_b  = (bf16*)alloc(512ull * 512 * 2);
  bf16*  fcW_b     = (bf16*)alloc(16000ull * 512 * 2);
  float* gh_ws     = (float*)alloc(32ull * 1536 * 4);
  float* hW_ws     = (float*)alloc(32ull * 512 * 4);
  unsigned* bar_ws = (unsigned*)alloc(4096ull * 4);      // enc @0, dec @2048

  embed_gather<<<1024, 256, 0, stream>>>(src, tgt, emb_src, emb_tgt, xs_b, ys_b);
  transpose_w<<<10240, 256, 0, stream>>>(enc_Whh, dec_Whh, attn_W, dec_Wih,
                                         encWhh_t, Wcat_t, Wihctx_t);
  pack_weights<<<36096, 256, 0, stream>>>(enc_Wih, dec_Wih, attn_W, fc_W,
                                          encWih_b, decWihY_b, attnWe_b, fcW_b,
                                          bar_ws);

  // enc_gi = xs @ enc_Wih^T + bih   (M=4096, N=1536, K=256)
  gemm_bt<<<dim3(12, 32), 256, 0, stream>>>(xs_b, 256, encWih_b, 256,
                                            enc_gi, 1536, enc_bih, 256);
  // dec_gi_y = ys @ dec_Wih[:, :E]^T + bih
  gemm_bt<<<dim3(12, 32), 256, 0, stream>>>(ys_b, 256, decWihY_b, 256,
                                            dec_gi_y, 1536, dec_bih, 256);

  // encoder recurrence: persistent kernel, per-batch barriers
  {
    unsigned* barf = bar_ws;
    void* args[] = {(void*)&enc_gi, (void*)&encWhh_t, (void*)&enc_bhh,
                    (void*)&enc_out, (void*)&enc_out_b, (void*)&barf};
    hipLaunchCooperativeKernel((void*)enc_loop, dim3(256), dim3(512),
                               args, 0, stream);
  }

  // enc_proj = enc_out @ We^T + attn_b  (M=4096, N=512, K=512)
  gemm_bt<<<dim3(4, 32), 256, 0, stream>>>(enc_out_b, 512, attnWe_b, 512,
                                           enc_proj, 512, attn_b, 512);

  // decoder recurrence: persistent kernel, per-batch barriers
  {
    unsigned* barf = bar_ws + 2048;
    void* args[] = {(void*)&enc_out, (void*)&enc_proj, (void*)&Wcat_t,
                    (void*)&Wihctx_t, (void*)&dec_gi_y, (void*)&dec_bhh,
                    (void*)&attn_v, (void*)&dec_seq, (void*)&dec_out_b,
                    (void*)&gh_ws, (void*)&hW_ws, (void*)&barf};
    hipLaunchCooperativeKernel((void*)dec_loop, dim3(256), dim3(512),
                               args, 0, stream);
  }

  // logits = dec_out @ fc_W^T + fc_b  (M=4096, N=16000, K=512) -> fp32 out
  gemm_bt<<<dim3(125, 32), 256, 0, stream>>>(dec_out_b, 512, fcW_b, 512,
                                             out, VTsz, fc_b, 512);
}